// Round 1
// baseline (769.824 us; speedup 1.0000x reference)
//
#include <hip/hip_runtime.h>
#include <hip/hip_bf16.h>
#include <math.h>

#define NEG_SLOPE 0.2f

static inline size_t align256(size_t x) { return (x + 255) & ~size_t(255); }

// ---------------- CSR build ----------------
__global__ void deg_kernel(const int* __restrict__ ei, int E, int N, int* __restrict__ deg) {
    int e = blockIdx.x * blockDim.x + threadIdx.x;
    int ET = E + N;
    if (e >= ET) return;
    int d = (e < E) ? ei[E + e] : (e - E);
    atomicAdd(&deg[d], 1);
}

__global__ void scan_kernel(const int* __restrict__ deg, int* __restrict__ offsets,
                            int* __restrict__ cursor, int n) {
    __shared__ int sd[1024];
    int carry = 0;
    for (int base = 0; base < n; base += 1024) {
        int i = base + (int)threadIdx.x;
        int v = (i < n) ? deg[i] : 0;
        sd[threadIdx.x] = v;
        __syncthreads();
        for (int off = 1; off < 1024; off <<= 1) {
            int t = (threadIdx.x >= (unsigned)off) ? sd[threadIdx.x - off] : 0;
            __syncthreads();
            sd[threadIdx.x] += t;
            __syncthreads();
        }
        int inc = sd[threadIdx.x];
        int total = sd[1023];
        int exc = inc - v + carry;
        if (i < n) { offsets[i] = exc; cursor[i] = exc; }
        carry += total;
        __syncthreads();
    }
    if (threadIdx.x == 0) offsets[n] = carry;
}

__global__ void place_kernel(const int* __restrict__ ei, int E, int N,
                             int* __restrict__ cursor, int* __restrict__ csr_src) {
    int e = blockIdx.x * blockDim.x + threadIdx.x;
    int ET = E + N;
    if (e >= ET) return;
    int s, d;
    if (e < E) { s = ei[e]; d = ei[E + e]; } else { s = d = e - E; }
    int pos = atomicAdd(&cursor[d], 1);
    csr_src[pos] = s;
}

// ---------------- layer 1 GEMM: h1 = x @ W1^T, + attention logit halves ----------------
__global__ __launch_bounds__(256) void gemm1_kernel(
    const float* __restrict__ x, const float* __restrict__ W1,
    const float* __restrict__ att_src, const float* __restrict__ att_dst,
    float* __restrict__ h1, float* __restrict__ asrc, float* __restrict__ adst, int N) {
    __shared__ float xs[8][128];
    int n0 = blockIdx.x * 8;
    int tid = threadIdx.x;
    for (int i = tid; i < 8 * 128; i += 256) {
        int r = i >> 7, k = i & 127;
        xs[r][k] = (n0 + r < N) ? x[(size_t)(n0 + r) * 128 + k] : 0.f;
    }
    __syncthreads();
    int m = tid;  // output channel 0..255
    float acc[8] = {0,0,0,0,0,0,0,0};
    const float* w = &W1[(size_t)m * 128];
    for (int k = 0; k < 128; ++k) {
        float wk = w[k];
        #pragma unroll
        for (int i = 0; i < 8; ++i) acc[i] += xs[i][k] * wk;
    }
    float as = att_src[m], ad = att_dst[m];
    #pragma unroll
    for (int i = 0; i < 8; ++i) {
        int n = n0 + i;
        if (n < N) h1[(size_t)n * 256 + m] = acc[i];
        float ps = acc[i] * as, pd = acc[i] * ad;
        #pragma unroll
        for (int off = 16; off >= 1; off >>= 1) {
            ps += __shfl_xor(ps, off, 32);
            pd += __shfl_xor(pd, off, 32);
        }
        if ((tid & 31) == 0 && n < N) {
            asrc[n * 8 + (m >> 5)] = ps;
            adst[n * 8 + (m >> 5)] = pd;
        }
    }
}

// ---------------- layer 1 aggregation (8 heads x 32 ch), fused bias + ELU ----------------
__global__ __launch_bounds__(256) void agg1_kernel(
    const float* __restrict__ h1, const float* __restrict__ asrc, const float* __restrict__ adst,
    const int* __restrict__ offsets, const int* __restrict__ csr_src,
    const float* __restrict__ b1, float* __restrict__ hout, int N) {
    int node = blockIdx.x;
    int tid = threadIdx.x;
    __shared__ float adst_sh[8];
    __shared__ float red[256];
    if (tid < 8) adst_sh[tid] = adst[node * 8 + tid];
    __syncthreads();
    int start = offsets[node];
    int deg = offsets[node + 1] - start;
    // phase A: per-head max over incoming edges
    {
        int h = tid & 7;
        float ah = adst_sh[h];
        float lm = -1e30f;
        for (int e = tid >> 3; e < deg; e += 32) {
            int s = csr_src[start + e];
            float v = asrc[s * 8 + h] + ah;
            v = v > 0.f ? v : NEG_SLOPE * v;
            lm = fmaxf(lm, v);
        }
        red[tid] = lm;
    }
    __syncthreads();
    #pragma unroll
    for (int off = 128; off >= 8; off >>= 1) {
        if (tid < off) red[tid] = fmaxf(red[tid], red[tid + off]);
        __syncthreads();
    }
    // phase B: weighted accumulation; thread = channel, head = tid>>5
    int hc = tid >> 5;
    float mh = red[hc];
    float ah = adst_sh[hc];
    float acc = 0.f, wsum = 0.f;
    for (int e = 0; e < deg; ++e) {
        int s = csr_src[start + e];
        float v = asrc[s * 8 + hc] + ah;
        v = v > 0.f ? v : NEG_SLOPE * v;
        float w = __expf(v - mh);
        wsum += w;
        acc += w * h1[(size_t)s * 256 + tid];
    }
    float o = acc / (wsum + 1e-16f) + b1[tid];
    hout[(size_t)node * 256 + tid] = o > 0.f ? o : (__expf(o) - 1.f);
}

// ---------------- layer 2 GEMM: h2 = helu @ W2^T, + attention logit halves ----------------
__global__ __launch_bounds__(256) void gemm2_kernel(
    const float* __restrict__ hin, const float* __restrict__ W2,
    const float* __restrict__ att_src, const float* __restrict__ att_dst,
    float* __restrict__ h2, float* __restrict__ asrc, float* __restrict__ adst, int N) {
    __shared__ float xs[16][256];
    int n0 = blockIdx.x * 16;
    int tid = threadIdx.x;
    for (int i = tid; i < 16 * 256; i += 256) {
        int r = i >> 8, k = i & 255;
        xs[r][k] = (n0 + r < N) ? hin[(size_t)(n0 + r) * 256 + k] : 0.f;
    }
    __syncthreads();
    int m = tid & 63;   // output channel
    int g = tid >> 6;   // wave id -> node group
    float acc[4] = {0,0,0,0};
    const float* w = &W2[(size_t)m * 256];
    for (int k = 0; k < 256; ++k) {
        float wk = w[k];
        #pragma unroll
        for (int i = 0; i < 4; ++i) acc[i] += xs[g * 4 + i][k] * wk;
    }
    float as = att_src[m], ad = att_dst[m];
    #pragma unroll
    for (int i = 0; i < 4; ++i) {
        int n = n0 + g * 4 + i;
        if (n < N) h2[(size_t)n * 64 + m] = acc[i];
        float ps = acc[i] * as, pd = acc[i] * ad;
        #pragma unroll
        for (int off = 32; off >= 1; off >>= 1) {
            ps += __shfl_xor(ps, off, 64);
            pd += __shfl_xor(pd, off, 64);
        }
        if (m == 0 && n < N) { asrc[n] = ps; adst[n] = pd; }
    }
}

// ---------------- layer 2 aggregation (1 head x 64 ch), fused bias ----------------
__global__ __launch_bounds__(64) void agg2_kernel(
    const float* __restrict__ h2, const float* __restrict__ asrc, const float* __restrict__ adst,
    const int* __restrict__ offsets, const int* __restrict__ csr_src,
    const float* __restrict__ b2, float* __restrict__ out2, int N) {
    int node = blockIdx.x;
    int lane = threadIdx.x;
    int start = offsets[node];
    int deg = offsets[node + 1] - start;
    float an = adst[node];
    float lm = -1e30f;
    for (int e = lane; e < deg; e += 64) {
        int s = csr_src[start + e];
        float v = asrc[s] + an;
        v = v > 0.f ? v : NEG_SLOPE * v;
        lm = fmaxf(lm, v);
    }
    #pragma unroll
    for (int off = 32; off >= 1; off >>= 1) lm = fmaxf(lm, __shfl_xor(lm, off, 64));
    float acc = 0.f, wsum = 0.f;
    for (int e = 0; e < deg; ++e) {
        int s = csr_src[start + e];
        float v = asrc[s] + an;
        v = v > 0.f ? v : NEG_SLOPE * v;
        float w = __expf(v - lm);
        wsum += w;
        acc += w * h2[(size_t)s * 64 + lane];
    }
    out2[(size_t)node * 64 + lane] = acc / (wsum + 1e-16f) + b2[lane];
}

// ---------------- FC + log_softmax ----------------
__global__ __launch_bounds__(256) void final_kernel(
    const float* __restrict__ out2, const float* __restrict__ fc_w,
    const float* __restrict__ fc_b, float* __restrict__ out, int N) {
    int tid = threadIdx.x;
    int node = blockIdx.x * 4 + (tid >> 6);
    int lane = tid & 63;
    if (node >= N) return;
    float v = out2[(size_t)node * 64 + lane];
    float p0 = v * fc_w[lane], p1 = v * fc_w[64 + lane];
    #pragma unroll
    for (int off = 32; off >= 1; off >>= 1) {
        p0 += __shfl_xor(p0, off, 64);
        p1 += __shfl_xor(p1, off, 64);
    }
    if (lane == 0) {
        float l0 = p0 + fc_b[0], l1 = p1 + fc_b[1];
        float mx = fmaxf(l0, l1);
        float lse = mx + logf(expf(l0 - mx) + expf(l1 - mx));
        out[(size_t)node * 2]     = l0 - lse;
        out[(size_t)node * 2 + 1] = l1 - lse;
    }
}

extern "C" void kernel_launch(void* const* d_in, const int* in_sizes, int n_in,
                              void* d_out, int out_size, void* d_ws, size_t ws_size,
                              hipStream_t stream) {
    const float* x        = (const float*)d_in[0];
    const int*   ei       = (const int*)d_in[1];
    const float* W1       = (const float*)d_in[2];
    const float* att_src1 = (const float*)d_in[3];
    const float* att_dst1 = (const float*)d_in[4];
    const float* b1       = (const float*)d_in[5];
    const float* W2       = (const float*)d_in[6];
    const float* att_src2 = (const float*)d_in[7];
    const float* att_dst2 = (const float*)d_in[8];
    const float* b2       = (const float*)d_in[9];
    const float* fc_w     = (const float*)d_in[10];
    const float* fc_b     = (const float*)d_in[11];
    float* out = (float*)d_out;

    int N = in_sizes[0] / 128;
    int E = in_sizes[1] / 2;
    int ET = E + N;

    char* p = (char*)d_ws;
    auto alloc = [&](size_t bytes) { char* r = p; p += align256(bytes); return r; };
    float* h1   = (float*)alloc((size_t)N * 256 * 4);
    float* helu = (float*)alloc((size_t)N * 256 * 4);
    float* h2   = (float*)alloc((size_t)N * 64 * 4);
    float* o2   = (float*)alloc((size_t)N * 64 * 4);
    float* as1  = (float*)alloc((size_t)N * 8 * 4);
    float* ad1  = (float*)alloc((size_t)N * 8 * 4);
    float* as2  = (float*)alloc((size_t)N * 4);
    float* ad2  = (float*)alloc((size_t)N * 4);
    int* deg    = (int*)alloc((size_t)N * 4);
    int* offs   = (int*)alloc((size_t)(N + 1) * 4);
    int* cursor = (int*)alloc((size_t)N * 4);
    int* csr    = (int*)alloc((size_t)ET * 4);

    hipMemsetAsync(deg, 0, (size_t)N * 4, stream);
    int eb = (ET + 255) / 256;
    deg_kernel<<<eb, 256, 0, stream>>>(ei, E, N, deg);
    scan_kernel<<<1, 1024, 0, stream>>>(deg, offs, cursor, N);
    place_kernel<<<eb, 256, 0, stream>>>(ei, E, N, cursor, csr);
    gemm1_kernel<<<(N + 7) / 8, 256, 0, stream>>>(x, W1, att_src1, att_dst1, h1, as1, ad1, N);
    agg1_kernel<<<N, 256, 0, stream>>>(h1, as1, ad1, offs, csr, b1, helu, N);
    gemm2_kernel<<<(N + 15) / 16, 256, 0, stream>>>(helu, W2, att_src2, att_dst2, h2, as2, ad2, N);
    agg2_kernel<<<N, 64, 0, stream>>>(h2, as2, ad2, offs, csr, b2, o2, N);
    final_kernel<<<(N + 3) / 4, 256, 0, stream>>>(o2, fc_w, fc_b, out, N);
}

// Round 2
// 564.154 us; speedup vs baseline: 1.3646x; 1.3646x over previous
//
#include <hip/hip_runtime.h>
#include <hip/hip_bf16.h>
#include <math.h>

#define NEG_SLOPE 0.2f

static inline size_t align256(size_t x) { return (x + 255) & ~size_t(255); }

__device__ __forceinline__ float bf2f(unsigned short u) {
    union { unsigned int i; float f; } v; v.i = ((unsigned int)u) << 16; return v.f;
}
__device__ __forceinline__ unsigned short f2bf(float f) {
    union { float f; unsigned int i; } v; v.f = f;
    unsigned int r = (v.i + 0x7FFFu + ((v.i >> 16) & 1u)) >> 16;
    return (unsigned short)r;
}

// ---------------- CSR build ----------------
__global__ void deg_kernel(const int* __restrict__ ei, int E, int N, int* __restrict__ deg) {
    int e = blockIdx.x * blockDim.x + threadIdx.x;
    int ET = E + N;
    if (e >= ET) return;
    int d = (e < E) ? ei[E + e] : (e - E);
    atomicAdd(&deg[d], 1);
}

__global__ __launch_bounds__(256) void scanA_kernel(const int* __restrict__ deg,
                                                    int* __restrict__ locinc,
                                                    int* __restrict__ bsum, int n) {
    __shared__ int sd[256];
    int tid = threadIdx.x;
    int i = blockIdx.x * 256 + tid;
    int v = (i < n) ? deg[i] : 0;
    sd[tid] = v;
    __syncthreads();
    for (int off = 1; off < 256; off <<= 1) {
        int t = (tid >= off) ? sd[tid - off] : 0;
        __syncthreads();
        sd[tid] += t;
        __syncthreads();
    }
    if (i < n) locinc[i] = sd[tid];
    if (tid == 255) bsum[blockIdx.x] = sd[255];
}

__global__ __launch_bounds__(256) void scanB_kernel(int* __restrict__ bsum, int nb, int* __restrict__ total) {
    __shared__ int sd[256];
    int tid = threadIdx.x;
    int carry = 0;
    for (int base = 0; base < nb; base += 256) {
        int i = base + tid;
        int v = (i < nb) ? bsum[i] : 0;
        sd[tid] = v;
        __syncthreads();
        for (int off = 1; off < 256; off <<= 1) {
            int t = (tid >= off) ? sd[tid - off] : 0;
            __syncthreads();
            sd[tid] += t;
            __syncthreads();
        }
        if (i < nb) bsum[i] = sd[tid] - v + carry;
        carry += sd[255];
        __syncthreads();
    }
    if (tid == 0) *total = carry;
}

__global__ __launch_bounds__(256) void scanC_kernel(const int* __restrict__ locinc,
                                                    const int* __restrict__ deg,
                                                    const int* __restrict__ bsum,
                                                    const int* __restrict__ total,
                                                    int* __restrict__ offsets,
                                                    int* __restrict__ cursor, int n) {
    int i = blockIdx.x * 256 + threadIdx.x;
    if (i < n) {
        int exc = locinc[i] - deg[i] + bsum[blockIdx.x];
        offsets[i] = exc;
        cursor[i] = exc;
    }
    if (blockIdx.x == 0 && threadIdx.x == 0) offsets[n] = *total;
}

__global__ void place_kernel(const int* __restrict__ ei, int E, int N,
                             int* __restrict__ cursor, int* __restrict__ csr_src) {
    int e = blockIdx.x * blockDim.x + threadIdx.x;
    int ET = E + N;
    if (e >= ET) return;
    int s, d;
    if (e < E) { s = ei[e]; d = ei[E + e]; } else { s = d = e - E; }
    int pos = atomicAdd(&cursor[d], 1);
    csr_src[pos] = s;
}

// ---------------- layer 1 GEMM: h1(bf16) = x @ W1^T ----------------
// tile: 32 nodes x 256 ch; thread: 8 nodes x 4 ch
__global__ __launch_bounds__(256) void gemm1_kernel(
    const float* __restrict__ x, const float* __restrict__ W1,
    unsigned short* __restrict__ h1, int N) {
    __shared__ float xs[32 * 128];
    int tid = threadIdx.x;
    int n0 = blockIdx.x * 32;
    const float4* x4 = (const float4*)x;
    float4* xs4 = (float4*)xs;
    for (int i = tid; i < 32 * 32; i += 256) {
        int row = i >> 5;
        float4 v = (n0 + row < N) ? x4[(size_t)(n0 + row) * 32 + (i & 31)] : float4{0, 0, 0, 0};
        xs4[i] = v;
    }
    __syncthreads();
    int m4 = tid & 63;
    int g = tid >> 6;
    float acc[8][4];
    #pragma unroll
    for (int i = 0; i < 8; ++i)
        #pragma unroll
        for (int c = 0; c < 4; ++c) acc[i][c] = 0.f;
    const float4* W4 = (const float4*)W1;
    for (int k4 = 0; k4 < 32; ++k4) {
        float4 wv[4];
        #pragma unroll
        for (int c = 0; c < 4; ++c) wv[c] = W4[(size_t)(m4 + 64 * c) * 32 + k4];
        #pragma unroll
        for (int i = 0; i < 8; ++i) {
            float4 xv = xs4[(g * 8 + i) * 32 + k4];
            #pragma unroll
            for (int c = 0; c < 4; ++c)
                acc[i][c] += xv.x * wv[c].x + xv.y * wv[c].y + xv.z * wv[c].z + xv.w * wv[c].w;
        }
    }
    #pragma unroll
    for (int i = 0; i < 8; ++i) {
        int n = n0 + g * 8 + i;
        if (n < N) {
            #pragma unroll
            for (int c = 0; c < 4; ++c)
                h1[(size_t)n * 256 + m4 + 64 * c] = f2bf(acc[i][c]);
        }
    }
}

// ---------------- attention logit halves from h1 (per node, per head) ----------------
__global__ __launch_bounds__(256) void att1_kernel(
    const unsigned short* __restrict__ h1, const float* __restrict__ att_src,
    const float* __restrict__ att_dst, float* __restrict__ asrc, float* __restrict__ adst, int N) {
    int idx = blockIdx.x * 256 + threadIdx.x;  // node*8 + head
    if (idx >= N * 8) return;
    int n = idx >> 3, h = idx & 7;
    const uint4* row = (const uint4*)&h1[(size_t)n * 256 + h * 32];
    float ps = 0.f, pd = 0.f;
    #pragma unroll
    for (int q = 0; q < 4; ++q) {
        uint4 u = row[q];
        const unsigned int* uw = (const unsigned int*)&u;
        #pragma unroll
        for (int w = 0; w < 4; ++w) {
            float f0 = bf2f((unsigned short)(uw[w] & 0xFFFF));
            float f1 = bf2f((unsigned short)(uw[w] >> 16));
            int ch = q * 8 + w * 2;
            ps += f0 * att_src[h * 32 + ch] + f1 * att_src[h * 32 + ch + 1];
            pd += f0 * att_dst[h * 32 + ch] + f1 * att_dst[h * 32 + ch + 1];
        }
    }
    asrc[idx] = ps;
    adst[idx] = pd;
}

// ---------------- layer 1 aggregation: 8 edges in flight, 16B bf16 loads ----------------
__global__ __launch_bounds__(256) void agg1_kernel(
    const unsigned short* __restrict__ h1, const float* __restrict__ asrc,
    const float* __restrict__ adst, const int* __restrict__ offsets,
    const int* __restrict__ csr_src, const float* __restrict__ b1,
    float* __restrict__ hout, int N) {
    int node = blockIdx.x;
    int tid = threadIdx.x;
    __shared__ float adst_sh[8];
    __shared__ float redmax[256];
    __shared__ float accred[256 * 9];  // padded stride 9: conflict-free
    __shared__ float wred[256];
    int start = offsets[node];
    int deg = offsets[node + 1] - start;
    if (tid < 8) adst_sh[tid] = adst[node * 8 + tid];
    __syncthreads();
    // phase A: per-head max (tid = e*8 + h)
    {
        int h = tid & 7;
        float ah = adst_sh[h];
        float lm = -1e30f;
        for (int e = tid >> 3; e < deg; e += 32) {
            int s = csr_src[start + e];
            float v = asrc[s * 8 + h] + ah;
            v = v > 0.f ? v : NEG_SLOPE * v;
            lm = fmaxf(lm, v);
        }
        redmax[tid] = lm;
    }
    __syncthreads();
    #pragma unroll
    for (int off = 128; off >= 8; off >>= 1) {
        if (tid < off) redmax[tid] = fmaxf(redmax[tid], redmax[tid + off]);
        __syncthreads();
    }
    // phase B: slot = tid>>5 (8 edges in flight), lane c = tid&31 -> ch 8c..8c+7
    int slot = tid >> 5;
    int c = tid & 31;
    int hd = c >> 2;
    float mh = redmax[hd];
    float ah = adst_sh[hd];
    float acc[8] = {0, 0, 0, 0, 0, 0, 0, 0};
    float wsum = 0.f;
    const uint4* h14 = (const uint4*)h1;  // row = 32 uint4 (256 bf16)
    for (int e = slot; e < deg; e += 8) {
        int s = csr_src[start + e];
        float v = asrc[s * 8 + hd] + ah;
        v = v > 0.f ? v : NEG_SLOPE * v;
        float w = __expf(v - mh);
        wsum += w;
        uint4 u = h14[(size_t)s * 32 + c];
        const unsigned int* uw = (const unsigned int*)&u;
        #pragma unroll
        for (int q = 0; q < 4; ++q) {
            acc[q * 2]     += w * bf2f((unsigned short)(uw[q] & 0xFFFF));
            acc[q * 2 + 1] += w * bf2f((unsigned short)(uw[q] >> 16));
        }
    }
    wred[tid] = wsum;
    #pragma unroll
    for (int j = 0; j < 8; ++j) accred[tid * 9 + j] = acc[j];
    __syncthreads();
    // final: thread owns channel ch = tid
    int ch = tid;
    int cc = ch >> 3, j = ch & 7;
    float a = 0.f;
    #pragma unroll
    for (int s2 = 0; s2 < 8; ++s2) a += accred[(s2 * 32 + cc) * 9 + j];
    int crep = (ch >> 5) << 2;
    float wt = 0.f;
    #pragma unroll
    for (int s2 = 0; s2 < 8; ++s2) wt += wred[s2 * 32 + crep];
    float o = a / (wt + 1e-16f) + b1[ch];
    hout[(size_t)node * 256 + ch] = o > 0.f ? o : (__expf(o) - 1.f);
}

// ---------------- layer 2 GEMM: h2(bf16) = helu @ W2^T ----------------
// tile: 64 nodes x 64 ch; thread: 8 nodes x 2 ch; K chunked by 64
__global__ __launch_bounds__(256) void gemm2_kernel(
    const float* __restrict__ hin, const float* __restrict__ W2,
    unsigned short* __restrict__ h2, int N) {
    __shared__ float xs[64 * 64];
    int tid = threadIdx.x;
    int n0 = blockIdx.x * 64;
    int c2 = tid & 31;
    int g = tid >> 5;
    float acc[8][2];
    #pragma unroll
    for (int i = 0; i < 8; ++i) { acc[i][0] = 0.f; acc[i][1] = 0.f; }
    const float4* hin4 = (const float4*)hin;
    const float4* W4 = (const float4*)W2;
    float4* xs4 = (float4*)xs;
    for (int kc = 0; kc < 4; ++kc) {
        __syncthreads();
        for (int i = tid; i < 64 * 16; i += 256) {
            int row = i >> 4, q = i & 15;
            float4 v = (n0 + row < N) ? hin4[(size_t)(n0 + row) * 64 + kc * 16 + q]
                                      : float4{0, 0, 0, 0};
            xs4[row * 16 + q] = v;
        }
        __syncthreads();
        for (int k4 = 0; k4 < 16; ++k4) {
            float4 wv0 = W4[(size_t)c2 * 64 + kc * 16 + k4];
            float4 wv1 = W4[(size_t)(c2 + 32) * 64 + kc * 16 + k4];
            #pragma unroll
            for (int i = 0; i < 8; ++i) {
                float4 xv = xs4[(g * 8 + i) * 16 + k4];
                acc[i][0] += xv.x * wv0.x + xv.y * wv0.y + xv.z * wv0.z + xv.w * wv0.w;
                acc[i][1] += xv.x * wv1.x + xv.y * wv1.y + xv.z * wv1.z + xv.w * wv1.w;
            }
        }
    }
    #pragma unroll
    for (int i = 0; i < 8; ++i) {
        int n = n0 + g * 8 + i;
        if (n < N) {
            h2[(size_t)n * 64 + c2]      = f2bf(acc[i][0]);
            h2[(size_t)n * 64 + c2 + 32] = f2bf(acc[i][1]);
        }
    }
}

// ---------------- layer 2 attention halves (1 head, 64 ch) ----------------
__global__ __launch_bounds__(256) void att2_kernel(
    const unsigned short* __restrict__ h2, const float* __restrict__ att_src,
    const float* __restrict__ att_dst, float* __restrict__ asrc, float* __restrict__ adst, int N) {
    int tid = threadIdx.x;
    int n = blockIdx.x * 4 + (tid >> 6);
    if (n >= N) return;
    int lane = tid & 63;
    float v = bf2f(h2[(size_t)n * 64 + lane]);
    float ps = v * att_src[lane], pd = v * att_dst[lane];
    #pragma unroll
    for (int off = 32; off >= 1; off >>= 1) {
        ps += __shfl_xor(ps, off, 64);
        pd += __shfl_xor(pd, off, 64);
    }
    if (lane == 0) { asrc[n] = ps; adst[n] = pd; }
}

// ---------------- layer 2 aggregation + FC + log_softmax (fused) ----------------
// one wave per node; slot = lane>>3 (8 edges in flight), c = lane&7 -> ch 8c..8c+7
__global__ __launch_bounds__(256) void agg2_kernel(
    const unsigned short* __restrict__ h2, const float* __restrict__ asrc,
    const float* __restrict__ adst, const int* __restrict__ offsets,
    const int* __restrict__ csr_src, const float* __restrict__ b2,
    const float* __restrict__ fc_w, const float* __restrict__ fc_b,
    float* __restrict__ out, int N) {
    int tid = threadIdx.x;
    int node = blockIdx.x * 4 + (tid >> 6);
    if (node >= N) return;
    int lane = tid & 63;
    int start = offsets[node];
    int deg = offsets[node + 1] - start;
    float an = adst[node];
    float lm = -1e30f;
    for (int e = lane; e < deg; e += 64) {
        int s = csr_src[start + e];
        float v = asrc[s] + an;
        v = v > 0.f ? v : NEG_SLOPE * v;
        lm = fmaxf(lm, v);
    }
    #pragma unroll
    for (int off = 32; off >= 1; off >>= 1) lm = fmaxf(lm, __shfl_xor(lm, off, 64));
    int slot = lane >> 3;
    int c = lane & 7;
    float acc[8] = {0, 0, 0, 0, 0, 0, 0, 0};
    float wsum = 0.f;
    const uint4* h24 = (const uint4*)h2;  // row = 8 uint4 (64 bf16)
    for (int e = slot; e < deg; e += 8) {
        int s = csr_src[start + e];
        float v = asrc[s] + an;
        v = v > 0.f ? v : NEG_SLOPE * v;
        float w = __expf(v - lm);
        wsum += w;
        uint4 u = h24[(size_t)s * 8 + c];
        const unsigned int* uw = (const unsigned int*)&u;
        #pragma unroll
        for (int q = 0; q < 4; ++q) {
            acc[q * 2]     += w * bf2f((unsigned short)(uw[q] & 0xFFFF));
            acc[q * 2 + 1] += w * bf2f((unsigned short)(uw[q] >> 16));
        }
    }
    // butterfly over slot bits -> every lane has full sums
    #pragma unroll
    for (int off = 8; off <= 32; off <<= 1) {
        wsum += __shfl_xor(wsum, off, 64);
        #pragma unroll
        for (int j = 0; j < 8; ++j) acc[j] += __shfl_xor(acc[j], off, 64);
    }
    float inv = 1.f / (wsum + 1e-16f);
    float p0 = 0.f, p1 = 0.f;
    #pragma unroll
    for (int j = 0; j < 8; ++j) {
        float o = acc[j] * inv + b2[c * 8 + j];
        p0 += o * fc_w[c * 8 + j];
        p1 += o * fc_w[64 + c * 8 + j];
    }
    // reduce over c (bits 0..2)
    #pragma unroll
    for (int off = 1; off <= 4; off <<= 1) {
        p0 += __shfl_xor(p0, off, 64);
        p1 += __shfl_xor(p1, off, 64);
    }
    if (lane == 0) {
        float l0 = p0 + fc_b[0], l1 = p1 + fc_b[1];
        float mx = fmaxf(l0, l1);
        float lse = mx + logf(expf(l0 - mx) + expf(l1 - mx));
        out[(size_t)node * 2]     = l0 - lse;
        out[(size_t)node * 2 + 1] = l1 - lse;
    }
}

extern "C" void kernel_launch(void* const* d_in, const int* in_sizes, int n_in,
                              void* d_out, int out_size, void* d_ws, size_t ws_size,
                              hipStream_t stream) {
    const float* x        = (const float*)d_in[0];
    const int*   ei       = (const int*)d_in[1];
    const float* W1       = (const float*)d_in[2];
    const float* att_src1 = (const float*)d_in[3];
    const float* att_dst1 = (const float*)d_in[4];
    const float* b1       = (const float*)d_in[5];
    const float* W2       = (const float*)d_in[6];
    const float* att_src2 = (const float*)d_in[7];
    const float* att_dst2 = (const float*)d_in[8];
    const float* b2       = (const float*)d_in[9];
    const float* fc_w     = (const float*)d_in[10];
    const float* fc_b     = (const float*)d_in[11];
    float* out = (float*)d_out;

    int N = in_sizes[0] / 128;
    int E = in_sizes[1] / 2;
    int ET = E + N;
    int nb = (N + 255) / 256;

    char* p = (char*)d_ws;
    auto alloc = [&](size_t bytes) { char* r = p; p += align256(bytes); return r; };
    unsigned short* h1 = (unsigned short*)alloc((size_t)N * 256 * 2);
    float* helu = (float*)alloc((size_t)N * 256 * 4);
    unsigned short* h2 = (unsigned short*)alloc((size_t)N * 64 * 2);
    float* as1  = (float*)alloc((size_t)N * 8 * 4);
    float* ad1  = (float*)alloc((size_t)N * 8 * 4);
    float* as2  = (float*)alloc((size_t)N * 4);
    float* ad2  = (float*)alloc((size_t)N * 4);
    int* deg    = (int*)alloc((size_t)N * 4);
    int* locinc = (int*)alloc((size_t)N * 4);
    int* bsum   = (int*)alloc((size_t)nb * 4);
    int* total  = (int*)alloc(4);
    int* offs   = (int*)alloc((size_t)(N + 1) * 4);
    int* cursor = (int*)alloc((size_t)N * 4);
    int* csr    = (int*)alloc((size_t)ET * 4);

    hipMemsetAsync(deg, 0, (size_t)N * 4, stream);
    int eb = (ET + 255) / 256;
    deg_kernel<<<eb, 256, 0, stream>>>(ei, E, N, deg);
    scanA_kernel<<<nb, 256, 0, stream>>>(deg, locinc, bsum, N);
    scanB_kernel<<<1, 256, 0, stream>>>(bsum, nb, total);
    scanC_kernel<<<nb, 256, 0, stream>>>(locinc, deg, bsum, total, offs, cursor, N);
    place_kernel<<<eb, 256, 0, stream>>>(ei, E, N, cursor, csr);
    gemm1_kernel<<<(N + 31) / 32, 256, 0, stream>>>(x, W1, h1, N);
    att1_kernel<<<(N * 8 + 255) / 256, 256, 0, stream>>>(h1, att_src1, att_dst1, as1, ad1, N);
    agg1_kernel<<<N, 256, 0, stream>>>(h1, as1, ad1, offs, csr, b1, helu, N);
    gemm2_kernel<<<(N + 63) / 64, 256, 0, stream>>>(helu, W2, h2, N);
    att2_kernel<<<(N + 3) / 4, 256, 0, stream>>>(h2, att_src2, att_dst2, as2, ad2, N);
    agg2_kernel<<<(N + 3) / 4, 256, 0, stream>>>(h2, as2, ad2, offs, csr, b2, fc_w, fc_b, out, N);
}

// Round 4
// 460.950 us; speedup vs baseline: 1.6701x; 1.2239x over previous
//
#include <hip/hip_runtime.h>
#include <hip/hip_bf16.h>
#include <math.h>

#define NEG_SLOPE 0.2f

static inline size_t align256(size_t x) { return (x + 255) & ~size_t(255); }

__device__ __forceinline__ float bf2f(unsigned short u) {
    union { unsigned int i; float f; } v; v.i = ((unsigned int)u) << 16; return v.f;
}
__device__ __forceinline__ unsigned short f2bf(float f) {
    union { float f; unsigned int i; } v; v.f = f;
    unsigned int r = (v.i + 0x7FFFu + ((v.i >> 16) & 1u)) >> 16;
    return (unsigned short)r;
}
__device__ __forceinline__ unsigned int pack2bf(float a, float b) {
    return (unsigned int)f2bf(a) | ((unsigned int)f2bf(b) << 16);
}

// ---------------- CSR build ----------------
__global__ void deg_kernel(const int* __restrict__ ei, int E, int N, int* __restrict__ deg) {
    int e = blockIdx.x * blockDim.x + threadIdx.x;
    int ET = E + N;
    if (e >= ET) return;
    int d = (e < E) ? ei[E + e] : (e - E);
    atomicAdd(&deg[d], 1);
}

__global__ __launch_bounds__(256) void scanA_kernel(const int* __restrict__ deg,
                                                    int* __restrict__ locinc,
                                                    int* __restrict__ bsum, int n) {
    __shared__ int sd[256];
    int tid = threadIdx.x;
    int i = blockIdx.x * 256 + tid;
    int v = (i < n) ? deg[i] : 0;
    sd[tid] = v;
    __syncthreads();
    for (int off = 1; off < 256; off <<= 1) {
        int t = (tid >= off) ? sd[tid - off] : 0;
        __syncthreads();
        sd[tid] += t;
        __syncthreads();
    }
    if (i < n) locinc[i] = sd[tid];
    if (tid == 255) bsum[blockIdx.x] = sd[255];
}

__global__ __launch_bounds__(256) void scanB_kernel(int* __restrict__ bsum, int nb, int* __restrict__ total) {
    __shared__ int sd[256];
    int tid = threadIdx.x;
    int carry = 0;
    for (int base = 0; base < nb; base += 256) {
        int i = base + tid;
        int v = (i < nb) ? bsum[i] : 0;
        sd[tid] = v;
        __syncthreads();
        for (int off = 1; off < 256; off <<= 1) {
            int t = (tid >= off) ? sd[tid - off] : 0;
            __syncthreads();
            sd[tid] += t;
            __syncthreads();
        }
        if (i < nb) bsum[i] = sd[tid] - v + carry;
        carry += sd[255];
        __syncthreads();
    }
    if (tid == 0) *total = carry;
}

__global__ __launch_bounds__(256) void scanC_kernel(const int* __restrict__ locinc,
                                                    const int* __restrict__ deg,
                                                    const int* __restrict__ bsum,
                                                    const int* __restrict__ total,
                                                    int* __restrict__ offsets,
                                                    int* __restrict__ cursor, int n) {
    int i = blockIdx.x * 256 + threadIdx.x;
    if (i < n) {
        int exc = locinc[i] - deg[i] + bsum[blockIdx.x];
        offsets[i] = exc;
        cursor[i] = exc;
    }
    if (blockIdx.x == 0 && threadIdx.x == 0) offsets[n] = *total;
}

__global__ void place_kernel(const int* __restrict__ ei, int E, int N,
                             int* __restrict__ cursor, int* __restrict__ csr_src) {
    int e = blockIdx.x * blockDim.x + threadIdx.x;
    int ET = E + N;
    if (e >= ET) return;
    int s, d;
    if (e < E) { s = ei[e]; d = ei[E + e]; } else { s = d = e - E; }
    int pos = atomicAdd(&cursor[d], 1);
    csr_src[pos] = s;
}

// ---------------- layer 1 GEMM: h1(bf16) = x @ W1^T, fused att halves ----------------
// BM=64, BN=256, BK=32; 256 thr; thread: 8 rows (4tr+i, 32+4tr+i) x 8 cols (4tc+j, 128+4tc+j)
__global__ __launch_bounds__(256) void gemm1_kernel(
    const float* __restrict__ x, const float* __restrict__ W1,
    const float* __restrict__ att_src, const float* __restrict__ att_dst,
    unsigned short* __restrict__ h1, float* __restrict__ asrc, float* __restrict__ adst, int N) {
    __shared__ float xsT[32][66];    // [k][m], pad 66
    __shared__ float wsT[32][258];   // [k][n], pad 258
    int tid = threadIdx.x;
    int n0 = blockIdx.x * 64;
    int tr = tid >> 5, tc = tid & 31;
    int rq = tid >> 3, q = tid & 7;
    float acc[8][8];
    #pragma unroll
    for (int i = 0; i < 8; ++i)
        #pragma unroll
        for (int j = 0; j < 8; ++j) acc[i][j] = 0.f;
    const float4* x4 = (const float4*)x;
    const float4* W4 = (const float4*)W1;
    for (int ks = 0; ks < 4; ++ks) {
        __syncthreads();
        #pragma unroll
        for (int i = 0; i < 2; ++i) {
            int r = rq + 32 * i;
            int n = n0 + r;
            float4 v = (n < N) ? x4[(size_t)n * 32 + ks * 8 + q] : float4{0, 0, 0, 0};
            xsT[4 * q + 0][r] = v.x; xsT[4 * q + 1][r] = v.y;
            xsT[4 * q + 2][r] = v.z; xsT[4 * q + 3][r] = v.w;
        }
        #pragma unroll
        for (int i = 0; i < 8; ++i) {
            int r = rq + 32 * i;
            float4 v = W4[(size_t)r * 32 + ks * 8 + q];
            wsT[4 * q + 0][r] = v.x; wsT[4 * q + 1][r] = v.y;
            wsT[4 * q + 2][r] = v.z; wsT[4 * q + 3][r] = v.w;
        }
        __syncthreads();
        #pragma unroll
        for (int kk = 0; kk < 32; ++kk) {
            float a[8], b[8];
            *(float2*)&a[0] = *(const float2*)&xsT[kk][4 * tr];
            *(float2*)&a[2] = *(const float2*)&xsT[kk][4 * tr + 2];
            *(float2*)&a[4] = *(const float2*)&xsT[kk][32 + 4 * tr];
            *(float2*)&a[6] = *(const float2*)&xsT[kk][32 + 4 * tr + 2];
            *(float2*)&b[0] = *(const float2*)&wsT[kk][4 * tc];
            *(float2*)&b[2] = *(const float2*)&wsT[kk][4 * tc + 2];
            *(float2*)&b[4] = *(const float2*)&wsT[kk][128 + 4 * tc];
            *(float2*)&b[6] = *(const float2*)&wsT[kk][128 + 4 * tc + 2];
            #pragma unroll
            for (int i = 0; i < 8; ++i)
                #pragma unroll
                for (int j = 0; j < 8; ++j) acc[i][j] += a[i] * b[j];
        }
    }
    // epilogue: bf16 store + fused attention halves
    int hA = tc >> 3, hB = 4 + (tc >> 3);
    int cb = (tc & 7) * 4;
    float sA[4], dA[4], sB[4], dB[4];
    #pragma unroll
    for (int j = 0; j < 4; ++j) {
        sA[j] = att_src[hA * 32 + cb + j];
        dA[j] = att_dst[hA * 32 + cb + j];
        sB[j] = att_src[hB * 32 + cb + j];
        dB[j] = att_dst[hB * 32 + cb + j];
    }
    #pragma unroll
    for (int i = 0; i < 8; ++i) {
        int r = (i < 4) ? (4 * tr + i) : (32 + 4 * tr + (i - 4));
        int n = n0 + r;
        bool ok = (n < N);
        if (ok) {
            uint2 u0, u1;
            u0.x = pack2bf(acc[i][0], acc[i][1]); u0.y = pack2bf(acc[i][2], acc[i][3]);
            u1.x = pack2bf(acc[i][4], acc[i][5]); u1.y = pack2bf(acc[i][6], acc[i][7]);
            *(uint2*)&h1[(size_t)n * 256 + 4 * tc] = u0;
            *(uint2*)&h1[(size_t)n * 256 + 128 + 4 * tc] = u1;
        }
        float psA = 0.f, pdA = 0.f, psB = 0.f, pdB = 0.f;
        #pragma unroll
        for (int j = 0; j < 4; ++j) {
            psA += acc[i][j] * sA[j];     pdA += acc[i][j] * dA[j];
            psB += acc[i][j + 4] * sB[j]; pdB += acc[i][j + 4] * dB[j];
        }
        #pragma unroll
        for (int off = 1; off <= 4; off <<= 1) {
            psA += __shfl_xor(psA, off, 64); pdA += __shfl_xor(pdA, off, 64);
            psB += __shfl_xor(psB, off, 64); pdB += __shfl_xor(pdB, off, 64);
        }
        if ((tc & 7) == 0 && ok) {
            asrc[n * 8 + hA] = psA; adst[n * 8 + hA] = pdA;
            asrc[n * 8 + hB] = psB; adst[n * 8 + hB] = pdB;
        }
    }
}

// ---------------- layer 1 aggregation: 8 edges in flight, 16B bf16 loads ----------------
__global__ __launch_bounds__(256) void agg1_kernel(
    const unsigned short* __restrict__ h1, const float* __restrict__ asrc,
    const float* __restrict__ adst, const int* __restrict__ offsets,
    const int* __restrict__ csr_src, const float* __restrict__ b1,
    float* __restrict__ hout, int N) {
    int node = blockIdx.x;
    int tid = threadIdx.x;
    __shared__ float adst_sh[8];
    __shared__ float redmax[256];
    __shared__ float accred[256 * 9];
    __shared__ float wred[256];
    int start = offsets[node];
    int deg = offsets[node + 1] - start;
    if (tid < 8) adst_sh[tid] = adst[node * 8 + tid];
    __syncthreads();
    {
        int h = tid & 7;
        float ah = adst_sh[h];
        float lm = -1e30f;
        for (int e = tid >> 3; e < deg; e += 32) {
            int s = csr_src[start + e];
            float v = asrc[s * 8 + h] + ah;
            v = v > 0.f ? v : NEG_SLOPE * v;
            lm = fmaxf(lm, v);
        }
        redmax[tid] = lm;
    }
    __syncthreads();
    #pragma unroll
    for (int off = 128; off >= 8; off >>= 1) {
        if (tid < off) redmax[tid] = fmaxf(redmax[tid], redmax[tid + off]);
        __syncthreads();
    }
    int slot = tid >> 5;
    int c = tid & 31;
    int hd = c >> 2;
    float mh = redmax[hd];
    float ah = adst_sh[hd];
    float acc[8] = {0, 0, 0, 0, 0, 0, 0, 0};
    float wsum = 0.f;
    const uint4* h14 = (const uint4*)h1;
    for (int e = slot; e < deg; e += 8) {
        int s = csr_src[start + e];
        float v = asrc[s * 8 + hd] + ah;
        v = v > 0.f ? v : NEG_SLOPE * v;
        float w = __expf(v - mh);
        wsum += w;
        uint4 u = h14[(size_t)s * 32 + c];
        const unsigned int* uw = (const unsigned int*)&u;
        #pragma unroll
        for (int qq = 0; qq < 4; ++qq) {
            acc[qq * 2]     += w * bf2f((unsigned short)(uw[qq] & 0xFFFF));
            acc[qq * 2 + 1] += w * bf2f((unsigned short)(uw[qq] >> 16));
        }
    }
    wred[tid] = wsum;
    #pragma unroll
    for (int j = 0; j < 8; ++j) accred[tid * 9 + j] = acc[j];
    __syncthreads();
    int ch = tid;
    int cc = ch >> 3, j = ch & 7;
    float a = 0.f;
    #pragma unroll
    for (int s2 = 0; s2 < 8; ++s2) a += accred[(s2 * 32 + cc) * 9 + j];
    int crep = (ch >> 5) << 2;
    float wt = 0.f;
    #pragma unroll
    for (int s2 = 0; s2 < 8; ++s2) wt += wred[s2 * 32 + crep];
    float o = a / (wt + 1e-16f) + b1[ch];
    hout[(size_t)node * 256 + ch] = o > 0.f ? o : (__expf(o) - 1.f);
}

// ---------------- layer 2 GEMM: h2(bf16) = helu @ W2^T, fused att halves ----------------
// BM=128, BN=64, BK=32; 256 thr; thread: 8 rows (4tr+i, 64+4tr+i) x 4 cols (4tc+j)
__global__ __launch_bounds__(256) void gemm2_kernel(
    const float* __restrict__ hin, const float* __restrict__ W2,
    const float* __restrict__ att_src, const float* __restrict__ att_dst,
    unsigned short* __restrict__ h2, float* __restrict__ asrc, float* __restrict__ adst, int N) {
    __shared__ float xsT[32][130];
    __shared__ float wsT[32][66];
    int tid = threadIdx.x;
    int n0 = blockIdx.x * 128;
    int tr = tid >> 4, tc = tid & 15;
    int rq = tid >> 3, q = tid & 7;
    float acc[8][4];
    #pragma unroll
    for (int i = 0; i < 8; ++i)
        #pragma unroll
        for (int j = 0; j < 4; ++j) acc[i][j] = 0.f;
    const float4* hin4 = (const float4*)hin;
    const float4* W4 = (const float4*)W2;
    for (int ks = 0; ks < 8; ++ks) {
        __syncthreads();
        #pragma unroll
        for (int i = 0; i < 4; ++i) {
            int r = rq + 32 * i;
            int n = n0 + r;
            float4 v = (n < N) ? hin4[(size_t)n * 64 + ks * 8 + q] : float4{0, 0, 0, 0};
            xsT[4 * q + 0][r] = v.x; xsT[4 * q + 1][r] = v.y;
            xsT[4 * q + 2][r] = v.z; xsT[4 * q + 3][r] = v.w;
        }
        #pragma unroll
        for (int i = 0; i < 2; ++i) {
            int r = rq + 32 * i;
            float4 v = W4[(size_t)r * 64 + ks * 8 + q];
            wsT[4 * q + 0][r] = v.x; wsT[4 * q + 1][r] = v.y;
            wsT[4 * q + 2][r] = v.z; wsT[4 * q + 3][r] = v.w;
        }
        __syncthreads();
        #pragma unroll
        for (int kk = 0; kk < 32; ++kk) {
            float a[8], b[4];
            *(float2*)&a[0] = *(const float2*)&xsT[kk][4 * tr];
            *(float2*)&a[2] = *(const float2*)&xsT[kk][4 * tr + 2];
            *(float2*)&a[4] = *(const float2*)&xsT[kk][64 + 4 * tr];
            *(float2*)&a[6] = *(const float2*)&xsT[kk][64 + 4 * tr + 2];
            *(float2*)&b[0] = *(const float2*)&wsT[kk][4 * tc];
            *(float2*)&b[2] = *(const float2*)&wsT[kk][4 * tc + 2];
            #pragma unroll
            for (int i = 0; i < 8; ++i)
                #pragma unroll
                for (int j = 0; j < 4; ++j) acc[i][j] += a[i] * b[j];
        }
    }
    float sC[4], dC[4];
    #pragma unroll
    for (int j = 0; j < 4; ++j) { sC[j] = att_src[4 * tc + j]; dC[j] = att_dst[4 * tc + j]; }
    #pragma unroll
    for (int i = 0; i < 8; ++i) {
        int r = (i < 4) ? (4 * tr + i) : (64 + 4 * tr + (i - 4));
        int n = n0 + r;
        bool ok = (n < N);
        if (ok) {
            uint2 u;
            u.x = pack2bf(acc[i][0], acc[i][1]); u.y = pack2bf(acc[i][2], acc[i][3]);
            *(uint2*)&h2[(size_t)n * 64 + 4 * tc] = u;
        }
        float ps = 0.f, pd = 0.f;
        #pragma unroll
        for (int j = 0; j < 4; ++j) { ps += acc[i][j] * sC[j]; pd += acc[i][j] * dC[j]; }
        #pragma unroll
        for (int off = 1; off <= 8; off <<= 1) {
            ps += __shfl_xor(ps, off, 64); pd += __shfl_xor(pd, off, 64);
        }
        if (tc == 0 && ok) { asrc[n] = ps; adst[n] = pd; }
    }
}

// ---------------- layer 2 aggregation + FC + log_softmax (fused) ----------------
__global__ __launch_bounds__(256) void agg2_kernel(
    const unsigned short* __restrict__ h2, const float* __restrict__ asrc,
    const float* __restrict__ adst, const int* __restrict__ offsets,
    const int* __restrict__ csr_src, const float* __restrict__ b2,
    const float* __restrict__ fc_w, const float* __restrict__ fc_b,
    float* __restrict__ out, int N) {
    int tid = threadIdx.x;
    int node = blockIdx.x * 4 + (tid >> 6);
    if (node >= N) return;
    int lane = tid & 63;
    int start = offsets[node];
    int deg = offsets[node + 1] - start;
    float an = adst[node];
    float lm = -1e30f;
    for (int e = lane; e < deg; e += 64) {
        int s = csr_src[start + e];
        float v = asrc[s] + an;
        v = v > 0.f ? v : NEG_SLOPE * v;
        lm = fmaxf(lm, v);
    }
    #pragma unroll
    for (int off = 32; off >= 1; off >>= 1) lm = fmaxf(lm, __shfl_xor(lm, off, 64));
    int slot = lane >> 3;
    int c = lane & 7;
    float acc[8] = {0, 0, 0, 0, 0, 0, 0, 0};
    float wsum = 0.f;
    const uint4* h24 = (const uint4*)h2;
    for (int e = slot; e < deg; e += 8) {
        int s = csr_src[start + e];
        float v = asrc[s] + an;
        v = v > 0.f ? v : NEG_SLOPE * v;
        float w = __expf(v - lm);
        wsum += w;
        uint4 u = h24[(size_t)s * 8 + c];
        const unsigned int* uw = (const unsigned int*)&u;
        #pragma unroll
        for (int qq = 0; qq < 4; ++qq) {
            acc[qq * 2]     += w * bf2f((unsigned short)(uw[qq] & 0xFFFF));
            acc[qq * 2 + 1] += w * bf2f((unsigned short)(uw[qq] >> 16));
        }
    }
    #pragma unroll
    for (int off = 8; off <= 32; off <<= 1) {
        wsum += __shfl_xor(wsum, off, 64);
        #pragma unroll
        for (int j = 0; j < 8; ++j) acc[j] += __shfl_xor(acc[j], off, 64);
    }
    float inv = 1.f / (wsum + 1e-16f);
    float p0 = 0.f, p1 = 0.f;
    #pragma unroll
    for (int j = 0; j < 8; ++j) {
        float o = acc[j] * inv + b2[c * 8 + j];
        p0 += o * fc_w[c * 8 + j];
        p1 += o * fc_w[64 + c * 8 + j];
    }
    #pragma unroll
    for (int off = 1; off <= 4; off <<= 1) {
        p0 += __shfl_xor(p0, off, 64);
        p1 += __shfl_xor(p1, off, 64);
    }
    if (lane == 0) {
        float l0 = p0 + fc_b[0], l1 = p1 + fc_b[1];
        float mx = fmaxf(l0, l1);
        float lse = mx + logf(expf(l0 - mx) + expf(l1 - mx));
        out[(size_t)node * 2]     = l0 - lse;
        out[(size_t)node * 2 + 1] = l1 - lse;
    }
}

extern "C" void kernel_launch(void* const* d_in, const int* in_sizes, int n_in,
                              void* d_out, int out_size, void* d_ws, size_t ws_size,
                              hipStream_t stream) {
    const float* x        = (const float*)d_in[0];
    const int*   ei       = (const int*)d_in[1];
    const float* W1       = (const float*)d_in[2];
    const float* att_src1 = (const float*)d_in[3];
    const float* att_dst1 = (const float*)d_in[4];
    const float* b1       = (const float*)d_in[5];
    const float* W2       = (const float*)d_in[6];
    const float* att_src2 = (const float*)d_in[7];
    const float* att_dst2 = (const float*)d_in[8];
    const float* b2       = (const float*)d_in[9];
    const float* fc_w     = (const float*)d_in[10];
    const float* fc_b     = (const float*)d_in[11];
    float* out = (float*)d_out;

    int N = in_sizes[0] / 128;
    int E = in_sizes[1] / 2;
    int ET = E + N;
    int nb = (N + 255) / 256;

    char* p = (char*)d_ws;
    auto alloc = [&](size_t bytes) { char* r = p; p += align256(bytes); return r; };
    unsigned short* h1 = (unsigned short*)alloc((size_t)N * 256 * 2);
    float* helu = (float*)alloc((size_t)N * 256 * 4);
    unsigned short* h2 = (unsigned short*)alloc((size_t)N * 64 * 2);
    float* as1  = (float*)alloc((size_t)N * 8 * 4);
    float* ad1  = (float*)alloc((size_t)N * 8 * 4);
    float* as2  = (float*)alloc((size_t)N * 4);
    float* ad2  = (float*)alloc((size_t)N * 4);
    int* deg    = (int*)alloc((size_t)N * 4);
    int* locinc = (int*)alloc((size_t)N * 4);
    int* bsum   = (int*)alloc((size_t)nb * 4);
    int* total  = (int*)alloc(4);
    int* offs   = (int*)alloc((size_t)(N + 1) * 4);
    int* cursor = (int*)alloc((size_t)N * 4);
    int* csr    = (int*)alloc((size_t)ET * 4);

    hipMemsetAsync(deg, 0, (size_t)N * 4, stream);
    int eb = (ET + 255) / 256;
    deg_kernel<<<eb, 256, 0, stream>>>(ei, E, N, deg);
    scanA_kernel<<<nb, 256, 0, stream>>>(deg, locinc, bsum, N);
    scanB_kernel<<<1, 256, 0, stream>>>(bsum, nb, total);
    scanC_kernel<<<nb, 256, 0, stream>>>(locinc, deg, bsum, total, offs, cursor, N);
    place_kernel<<<eb, 256, 0, stream>>>(ei, E, N, cursor, csr);
    gemm1_kernel<<<(N + 63) / 64, 256, 0, stream>>>(x, W1, att_src1, att_dst1, h1, as1, ad1, N);
    agg1_kernel<<<N, 256, 0, stream>>>(h1, as1, ad1, offs, csr, b1, helu, N);
    gemm2_kernel<<<(N + 127) / 128, 256, 0, stream>>>(helu, W2, att_src2, att_dst2, h2, as2, ad2, N);
    agg2_kernel<<<(N + 3) / 4, 256, 0, stream>>>(h2, as2, ad2, offs, csr, b2, fc_w, fc_b, out, N);
}

// Round 5
// 399.387 us; speedup vs baseline: 1.9275x; 1.1541x over previous
//
#include <hip/hip_runtime.h>
#include <hip/hip_bf16.h>
#include <math.h>

#define NEG_SLOPE 0.2f

typedef _Float16 half8 __attribute__((ext_vector_type(8)));
typedef float floatx4 __attribute__((ext_vector_type(4)));

static inline size_t align256(size_t x) { return (x + 255) & ~size_t(255); }

// ---------------- f32 -> f16 conversion ----------------
__global__ __launch_bounds__(256) void cvt_kernel(const float* __restrict__ a,
                                                  _Float16* __restrict__ b, int n4) {
    int i = blockIdx.x * blockDim.x + threadIdx.x;
    int stride = gridDim.x * blockDim.x;
    const float4* a4 = (const float4*)a;
    uint2* b4 = (uint2*)b;
    for (; i < n4; i += stride) {
        float4 v = a4[i];
        uint2 o;
        _Float16* h = (_Float16*)&o;
        h[0] = (_Float16)v.x; h[1] = (_Float16)v.y;
        h[2] = (_Float16)v.z; h[3] = (_Float16)v.w;
        b4[i] = o;
    }
}

// ---------------- CSR build ----------------
__global__ void deg_kernel(const int* __restrict__ ei, int E, int N, int* __restrict__ deg) {
    int e = blockIdx.x * blockDim.x + threadIdx.x;
    int ET = E + N;
    if (e >= ET) return;
    int d = (e < E) ? ei[E + e] : (e - E);
    atomicAdd(&deg[d], 1);
}

__global__ __launch_bounds__(256) void scanA_kernel(const int* __restrict__ deg,
                                                    int* __restrict__ locinc,
                                                    int* __restrict__ bsum, int n) {
    __shared__ int sd[256];
    int tid = threadIdx.x;
    int i = blockIdx.x * 256 + tid;
    int v = (i < n) ? deg[i] : 0;
    sd[tid] = v;
    __syncthreads();
    for (int off = 1; off < 256; off <<= 1) {
        int t = (tid >= off) ? sd[tid - off] : 0;
        __syncthreads();
        sd[tid] += t;
        __syncthreads();
    }
    if (i < n) locinc[i] = sd[tid];
    if (tid == 255) bsum[blockIdx.x] = sd[255];
}

__global__ __launch_bounds__(256) void scanB_kernel(int* __restrict__ bsum, int nb, int* __restrict__ total) {
    __shared__ int sd[256];
    int tid = threadIdx.x;
    int carry = 0;
    for (int base = 0; base < nb; base += 256) {
        int i = base + tid;
        int v = (i < nb) ? bsum[i] : 0;
        sd[tid] = v;
        __syncthreads();
        for (int off = 1; off < 256; off <<= 1) {
            int t = (tid >= off) ? sd[tid - off] : 0;
            __syncthreads();
            sd[tid] += t;
            __syncthreads();
        }
        if (i < nb) bsum[i] = sd[tid] - v + carry;
        carry += sd[255];
        __syncthreads();
    }
    if (tid == 0) *total = carry;
}

__global__ __launch_bounds__(256) void scanC_kernel(const int* __restrict__ locinc,
                                                    const int* __restrict__ deg,
                                                    const int* __restrict__ bsum,
                                                    const int* __restrict__ total,
                                                    int* __restrict__ offsets,
                                                    int* __restrict__ cursor, int n) {
    int i = blockIdx.x * 256 + threadIdx.x;
    if (i < n) {
        int exc = locinc[i] - deg[i] + bsum[blockIdx.x];
        offsets[i] = exc;
        cursor[i] = exc;
    }
    if (blockIdx.x == 0 && threadIdx.x == 0) offsets[n] = *total;
}

__global__ void place_kernel(const int* __restrict__ ei, int E, int N,
                             int* __restrict__ cursor, int* __restrict__ csr_src) {
    int e = blockIdx.x * blockDim.x + threadIdx.x;
    int ET = E + N;
    if (e >= ET) return;
    int s, d;
    if (e < E) { s = ei[e]; d = ei[E + e]; } else { s = d = e - E; }
    int pos = atomicAdd(&cursor[d], 1);
    csr_src[pos] = s;
}

// ---------------- layer 1 GEMM (MFMA f16): h1 = x @ W1^T, fused att halves ----------------
// block = 4 waves, 32 rows; wave w: rows n0+(w>>1)*16, cols (w&1)*128 + ct*16, ct=0..7
__global__ __launch_bounds__(256) void gemm1_kernel(
    const _Float16* __restrict__ xf, const _Float16* __restrict__ w1f,
    const float* __restrict__ att_src, const float* __restrict__ att_dst,
    _Float16* __restrict__ h1, float* __restrict__ asrc, float* __restrict__ adst, int N) {
    int tid = threadIdx.x;
    int w = tid >> 6, l = tid & 63;
    int g = l >> 4, li = l & 15;
    int n0 = blockIdx.x * 32;
    int row = n0 + (w >> 1) * 16 + li;
    int rowc = row < N ? row : N - 1;
    int colbase = (w & 1) * 128;

    half8 af[4];
    #pragma unroll
    for (int kc = 0; kc < 4; ++kc)
        af[kc] = *(const half8*)&xf[(size_t)rowc * 128 + kc * 32 + g * 8];

    floatx4 acc[8];
    #pragma unroll
    for (int ct = 0; ct < 8; ++ct) acc[ct] = (floatx4){0.f, 0.f, 0.f, 0.f};

    #pragma unroll
    for (int ct = 0; ct < 8; ++ct) {
        int col = colbase + ct * 16 + li;
        const _Float16* wp = &w1f[(size_t)col * 128 + g * 8];
        #pragma unroll
        for (int kc = 0; kc < 4; ++kc) {
            half8 bf = *(const half8*)&wp[kc * 32];
            acc[ct] = __builtin_amdgcn_mfma_f32_16x16x32_f16(af[kc], bf, acc[ct], 0, 0, 0);
        }
    }

    // C layout: acc[ct][j] = C[(w>>1)*16 + g*4 + j][colbase + ct*16 + li]
    int rowOut0 = n0 + (w >> 1) * 16 + g * 4;
    #pragma unroll
    for (int ct = 0; ct < 8; ++ct) {
        int col = colbase + ct * 16 + li;
        #pragma unroll
        for (int j = 0; j < 4; ++j) {
            int n = rowOut0 + j;
            if (n < N) h1[(size_t)n * 256 + col] = (_Float16)acc[ct][j];
        }
    }
    // fused attention halves: head = (w&1)*4 + hh; cols = ct in {2hh, 2hh+1}
    #pragma unroll
    for (int hh = 0; hh < 4; ++hh) {
        int head = (w & 1) * 4 + hh;
        int c0 = colbase + (2 * hh) * 16 + li;
        float s0 = att_src[c0], s1 = att_src[c0 + 16];
        float d0 = att_dst[c0], d1 = att_dst[c0 + 16];
        #pragma unroll
        for (int j = 0; j < 4; ++j) {
            float ps = acc[2 * hh][j] * s0 + acc[2 * hh + 1][j] * s1;
            float pd = acc[2 * hh][j] * d0 + acc[2 * hh + 1][j] * d1;
            #pragma unroll
            for (int off = 1; off <= 8; off <<= 1) {
                ps += __shfl_xor(ps, off, 64);
                pd += __shfl_xor(pd, off, 64);
            }
            int n = rowOut0 + j;
            if (li == 0 && n < N) {
                asrc[n * 8 + head] = ps;
                adst[n * 8 + head] = pd;
            }
        }
    }
}

// ---------------- layer 1 aggregation: 8 edges in flight, 16B f16 loads ----------------
__global__ __launch_bounds__(256) void agg1_kernel(
    const _Float16* __restrict__ h1, const float* __restrict__ asrc,
    const float* __restrict__ adst, const int* __restrict__ offsets,
    const int* __restrict__ csr_src, const float* __restrict__ b1,
    _Float16* __restrict__ hout, int N) {
    int node = blockIdx.x;
    int tid = threadIdx.x;
    __shared__ float adst_sh[8];
    __shared__ float redmax[256];
    __shared__ float accred[256 * 9];
    __shared__ float wred[256];
    int start = offsets[node];
    int deg = offsets[node + 1] - start;
    if (tid < 8) adst_sh[tid] = adst[node * 8 + tid];
    __syncthreads();
    {
        int h = tid & 7;
        float ah = adst_sh[h];
        float lm = -1e30f;
        for (int e = tid >> 3; e < deg; e += 32) {
            int s = csr_src[start + e];
            float v = asrc[s * 8 + h] + ah;
            v = v > 0.f ? v : NEG_SLOPE * v;
            lm = fmaxf(lm, v);
        }
        redmax[tid] = lm;
    }
    __syncthreads();
    #pragma unroll
    for (int off = 128; off >= 8; off >>= 1) {
        if (tid < off) redmax[tid] = fmaxf(redmax[tid], redmax[tid + off]);
        __syncthreads();
    }
    int slot = tid >> 5;
    int c = tid & 31;
    int hd = c >> 2;
    float mh = redmax[hd];
    float ah = adst_sh[hd];
    float acc[8] = {0, 0, 0, 0, 0, 0, 0, 0};
    float wsum = 0.f;
    const uint4* h14 = (const uint4*)h1;
    for (int e = slot; e < deg; e += 8) {
        int s = csr_src[start + e];
        float v = asrc[s * 8 + hd] + ah;
        v = v > 0.f ? v : NEG_SLOPE * v;
        float wgt = __expf(v - mh);
        wsum += wgt;
        uint4 u = h14[(size_t)s * 32 + c];
        const _Float16* hp = (const _Float16*)&u;
        #pragma unroll
        for (int qq = 0; qq < 8; ++qq) acc[qq] += wgt * (float)hp[qq];
    }
    wred[tid] = wsum;
    #pragma unroll
    for (int j = 0; j < 8; ++j) accred[tid * 9 + j] = acc[j];
    __syncthreads();
    int ch = tid;
    int cc = ch >> 3, j = ch & 7;
    float a = 0.f;
    #pragma unroll
    for (int s2 = 0; s2 < 8; ++s2) a += accred[(s2 * 32 + cc) * 9 + j];
    int crep = (ch >> 5) << 2;
    float wt = 0.f;
    #pragma unroll
    for (int s2 = 0; s2 < 8; ++s2) wt += wred[s2 * 32 + crep];
    float o = a / (wt + 1e-16f) + b1[ch];
    o = o > 0.f ? o : (__expf(o) - 1.f);
    hout[(size_t)node * 256 + ch] = (_Float16)o;
}

// ---------------- layer 2 GEMM (MFMA f16): h2 = helu @ W2^T, fused att halves ----------------
// block = 4 waves, 32 rows; wave w: rows n0+(w>>1)*16, cols (w&1)*32 + ct*16, ct=0..1
__global__ __launch_bounds__(256) void gemm2_kernel(
    const _Float16* __restrict__ hf, const _Float16* __restrict__ w2f,
    const float* __restrict__ att_src, const float* __restrict__ att_dst,
    _Float16* __restrict__ h2, float* __restrict__ asrc, float* __restrict__ adst, int N) {
    __shared__ float a2s[2][2][32];
    int tid = threadIdx.x;
    int w = tid >> 6, l = tid & 63;
    int g = l >> 4, li = l & 15;
    int n0 = blockIdx.x * 32;
    int row = n0 + (w >> 1) * 16 + li;
    int rowc = row < N ? row : N - 1;
    int colbase = (w & 1) * 32;

    floatx4 acc[2];
    acc[0] = (floatx4){0.f, 0.f, 0.f, 0.f};
    acc[1] = (floatx4){0.f, 0.f, 0.f, 0.f};

    #pragma unroll
    for (int kc = 0; kc < 8; ++kc) {
        half8 af = *(const half8*)&hf[(size_t)rowc * 256 + kc * 32 + g * 8];
        #pragma unroll
        for (int ct = 0; ct < 2; ++ct) {
            int col = colbase + ct * 16 + li;
            half8 bf = *(const half8*)&w2f[(size_t)col * 256 + kc * 32 + g * 8];
            acc[ct] = __builtin_amdgcn_mfma_f32_16x16x32_f16(af, bf, acc[ct], 0, 0, 0);
        }
    }

    int rowl0 = (w >> 1) * 16 + g * 4;
    #pragma unroll
    for (int ct = 0; ct < 2; ++ct) {
        int col = colbase + ct * 16 + li;
        #pragma unroll
        for (int j = 0; j < 4; ++j) {
            int n = n0 + rowl0 + j;
            if (n < N) h2[(size_t)n * 64 + col] = (_Float16)acc[ct][j];
        }
    }
    float s0 = att_src[colbase + li], s1 = att_src[colbase + 16 + li];
    float d0 = att_dst[colbase + li], d1 = att_dst[colbase + 16 + li];
    #pragma unroll
    for (int j = 0; j < 4; ++j) {
        float ps = acc[0][j] * s0 + acc[1][j] * s1;
        float pd = acc[0][j] * d0 + acc[1][j] * d1;
        #pragma unroll
        for (int off = 1; off <= 8; off <<= 1) {
            ps += __shfl_xor(ps, off, 64);
            pd += __shfl_xor(pd, off, 64);
        }
        if (li == 0) {
            a2s[w & 1][0][rowl0 + j] = ps;
            a2s[w & 1][1][rowl0 + j] = pd;
        }
    }
    __syncthreads();
    if (tid < 64) {
        int rl = tid & 31, sd = tid >> 5;
        float v = a2s[0][sd][rl] + a2s[1][sd][rl];
        int n = n0 + rl;
        if (n < N) (sd ? adst : asrc)[n] = v;
    }
}

// ---------------- layer 2 aggregation + FC + log_softmax (fused) ----------------
__global__ __launch_bounds__(256) void agg2_kernel(
    const _Float16* __restrict__ h2, const float* __restrict__ asrc,
    const float* __restrict__ adst, const int* __restrict__ offsets,
    const int* __restrict__ csr_src, const float* __restrict__ b2,
    const float* __restrict__ fc_w, const float* __restrict__ fc_b,
    float* __restrict__ out, int N) {
    int tid = threadIdx.x;
    int node = blockIdx.x * 4 + (tid >> 6);
    if (node >= N) return;
    int lane = tid & 63;
    int start = offsets[node];
    int deg = offsets[node + 1] - start;
    float an = adst[node];
    float lm = -1e30f;
    for (int e = lane; e < deg; e += 64) {
        int s = csr_src[start + e];
        float v = asrc[s] + an;
        v = v > 0.f ? v : NEG_SLOPE * v;
        lm = fmaxf(lm, v);
    }
    #pragma unroll
    for (int off = 32; off >= 1; off >>= 1) lm = fmaxf(lm, __shfl_xor(lm, off, 64));
    int slot = lane >> 3;
    int c = lane & 7;
    float acc[8] = {0, 0, 0, 0, 0, 0, 0, 0};
    float wsum = 0.f;
    const uint4* h24 = (const uint4*)h2;
    for (int e = slot; e < deg; e += 8) {
        int s = csr_src[start + e];
        float v = asrc[s] + an;
        v = v > 0.f ? v : NEG_SLOPE * v;
        float wgt = __expf(v - lm);
        wsum += wgt;
        uint4 u = h24[(size_t)s * 8 + c];
        const _Float16* hp = (const _Float16*)&u;
        #pragma unroll
        for (int qq = 0; qq < 8; ++qq) acc[qq] += wgt * (float)hp[qq];
    }
    #pragma unroll
    for (int off = 8; off <= 32; off <<= 1) {
        wsum += __shfl_xor(wsum, off, 64);
        #pragma unroll
        for (int j = 0; j < 8; ++j) acc[j] += __shfl_xor(acc[j], off, 64);
    }
    float inv = 1.f / (wsum + 1e-16f);
    float p0 = 0.f, p1 = 0.f;
    #pragma unroll
    for (int j = 0; j < 8; ++j) {
        float o = acc[j] * inv + b2[c * 8 + j];
        p0 += o * fc_w[c * 8 + j];
        p1 += o * fc_w[64 + c * 8 + j];
    }
    #pragma unroll
    for (int off = 1; off <= 4; off <<= 1) {
        p0 += __shfl_xor(p0, off, 64);
        p1 += __shfl_xor(p1, off, 64);
    }
    if (lane == 0) {
        float l0 = p0 + fc_b[0], l1 = p1 + fc_b[1];
        float mx = fmaxf(l0, l1);
        float lse = mx + logf(expf(l0 - mx) + expf(l1 - mx));
        out[(size_t)node * 2]     = l0 - lse;
        out[(size_t)node * 2 + 1] = l1 - lse;
    }
}

extern "C" void kernel_launch(void* const* d_in, const int* in_sizes, int n_in,
                              void* d_out, int out_size, void* d_ws, size_t ws_size,
                              hipStream_t stream) {
    const float* x        = (const float*)d_in[0];
    const int*   ei       = (const int*)d_in[1];
    const float* W1       = (const float*)d_in[2];
    const float* att_src1 = (const float*)d_in[3];
    const float* att_dst1 = (const float*)d_in[4];
    const float* b1       = (const float*)d_in[5];
    const float* W2       = (const float*)d_in[6];
    const float* att_src2 = (const float*)d_in[7];
    const float* att_dst2 = (const float*)d_in[8];
    const float* b2       = (const float*)d_in[9];
    const float* fc_w     = (const float*)d_in[10];
    const float* fc_b     = (const float*)d_in[11];
    float* out = (float*)d_out;

    int N = in_sizes[0] / 128;
    int E = in_sizes[1] / 2;
    int ET = E + N;
    int nb = (N + 255) / 256;

    char* p = (char*)d_ws;
    auto alloc = [&](size_t bytes) { char* r = p; p += align256(bytes); return r; };
    _Float16* xf16 = (_Float16*)alloc((size_t)N * 128 * 2);
    _Float16* w1f  = (_Float16*)alloc((size_t)256 * 128 * 2);
    _Float16* w2f  = (_Float16*)alloc((size_t)64 * 256 * 2);
    _Float16* h1   = (_Float16*)alloc((size_t)N * 256 * 2);
    _Float16* helu = (_Float16*)alloc((size_t)N * 256 * 2);
    _Float16* h2   = (_Float16*)alloc((size_t)N * 64 * 2);
    float* as1  = (float*)alloc((size_t)N * 8 * 4);
    float* ad1  = (float*)alloc((size_t)N * 8 * 4);
    float* as2  = (float*)alloc((size_t)N * 4);
    float* ad2  = (float*)alloc((size_t)N * 4);
    int* deg    = (int*)alloc((size_t)N * 4);
    int* locinc = (int*)alloc((size_t)N * 4);
    int* bsum   = (int*)alloc((size_t)nb * 4);
    int* total  = (int*)alloc(4);
    int* offs   = (int*)alloc((size_t)(N + 1) * 4);
    int* cursor = (int*)alloc((size_t)N * 4);
    int* csr    = (int*)alloc((size_t)ET * 4);

    hipMemsetAsync(deg, 0, (size_t)N * 4, stream);
    int eb = (ET + 255) / 256;
    // conversions
    cvt_kernel<<<2048, 256, 0, stream>>>(x, xf16, N * 128 / 4);
    cvt_kernel<<<32, 256, 0, stream>>>(W1, w1f, 256 * 128 / 4);
    cvt_kernel<<<16, 256, 0, stream>>>(W2, w2f, 64 * 256 / 4);
    // CSR
    deg_kernel<<<eb, 256, 0, stream>>>(ei, E, N, deg);
    scanA_kernel<<<nb, 256, 0, stream>>>(deg, locinc, bsum, N);
    scanB_kernel<<<1, 256, 0, stream>>>(bsum, nb, total);
    scanC_kernel<<<nb, 256, 0, stream>>>(locinc, deg, bsum, total, offs, cursor, N);
    place_kernel<<<eb, 256, 0, stream>>>(ei, E, N, cursor, csr);
    // layers
    gemm1_kernel<<<(N + 31) / 32, 256, 0, stream>>>(xf16, w1f, att_src1, att_dst1, h1, as1, ad1, N);
    agg1_kernel<<<N, 256, 0, stream>>>(h1, as1, ad1, offs, csr, b1, helu, N);
    gemm2_kernel<<<(N + 31) / 32, 256, 0, stream>>>(helu, w2f, att_src2, att_dst2, h2, as2, ad2, N);
    agg2_kernel<<<(N + 3) / 4, 256, 0, stream>>>(h2, as2, ad2, offs, csr, b2, fc_w, fc_b, out, N);
}

// Round 6
// 348.153 us; speedup vs baseline: 2.2112x; 1.1472x over previous
//
#include <hip/hip_runtime.h>
#include <hip/hip_bf16.h>
#include <math.h>

#define NEG_SLOPE 0.2f

typedef _Float16 half8 __attribute__((ext_vector_type(8)));
typedef float floatx4 __attribute__((ext_vector_type(4)));

static inline size_t align256(size_t x) { return (x + 255) & ~size_t(255); }

// ---------------- f32 -> f16 conversion ----------------
__global__ __launch_bounds__(256) void cvt_kernel(const float* __restrict__ a,
                                                  _Float16* __restrict__ b, int n4) {
    int i = blockIdx.x * blockDim.x + threadIdx.x;
    int stride = gridDim.x * blockDim.x;
    const float4* a4 = (const float4*)a;
    uint2* b4 = (uint2*)b;
    for (; i < n4; i += stride) {
        float4 v = a4[i];
        uint2 o;
        _Float16* h = (_Float16*)&o;
        h[0] = (_Float16)v.x; h[1] = (_Float16)v.y;
        h[2] = (_Float16)v.z; h[3] = (_Float16)v.w;
        b4[i] = o;
    }
}

// ---------------- CSR build ----------------
__global__ void deg_kernel(const int* __restrict__ ei, int E, int N, int* __restrict__ deg) {
    int e = blockIdx.x * blockDim.x + threadIdx.x;
    int ET = E + N;
    if (e >= ET) return;
    int d = (e < E) ? ei[E + e] : (e - E);
    atomicAdd(&deg[d], 1);
}

__global__ __launch_bounds__(256) void scanA_kernel(const int* __restrict__ deg,
                                                    int* __restrict__ locinc,
                                                    int* __restrict__ bsum, int n) {
    __shared__ int sd[256];
    int tid = threadIdx.x;
    int i = blockIdx.x * 256 + tid;
    int v = (i < n) ? deg[i] : 0;
    sd[tid] = v;
    __syncthreads();
    for (int off = 1; off < 256; off <<= 1) {
        int t = (tid >= off) ? sd[tid - off] : 0;
        __syncthreads();
        sd[tid] += t;
        __syncthreads();
    }
    if (i < n) locinc[i] = sd[tid];
    if (tid == 255) bsum[blockIdx.x] = sd[255];
}

__global__ __launch_bounds__(256) void scanB_kernel(int* __restrict__ bsum, int nb, int* __restrict__ total) {
    __shared__ int sd[256];
    int tid = threadIdx.x;
    int carry = 0;
    for (int base = 0; base < nb; base += 256) {
        int i = base + tid;
        int v = (i < nb) ? bsum[i] : 0;
        sd[tid] = v;
        __syncthreads();
        for (int off = 1; off < 256; off <<= 1) {
            int t = (tid >= off) ? sd[tid - off] : 0;
            __syncthreads();
            sd[tid] += t;
            __syncthreads();
        }
        if (i < nb) bsum[i] = sd[tid] - v + carry;
        carry += sd[255];
        __syncthreads();
    }
    if (tid == 0) *total = carry;
}

__global__ __launch_bounds__(256) void scanC_kernel(const int* __restrict__ locinc,
                                                    const int* __restrict__ deg,
                                                    const int* __restrict__ bsum,
                                                    const int* __restrict__ total,
                                                    int* __restrict__ offsets,
                                                    int* __restrict__ cursor, int n) {
    int i = blockIdx.x * 256 + threadIdx.x;
    if (i < n) {
        int exc = locinc[i] - deg[i] + bsum[blockIdx.x];
        offsets[i] = exc;
        cursor[i] = exc;
    }
    if (blockIdx.x == 0 && threadIdx.x == 0) offsets[n] = *total;
}

__global__ void place_kernel(const int* __restrict__ ei, int E, int N,
                             int* __restrict__ cursor, int* __restrict__ csr_src) {
    int e = blockIdx.x * blockDim.x + threadIdx.x;
    int ET = E + N;
    if (e >= ET) return;
    int s, d;
    if (e < E) { s = ei[e]; d = ei[E + e]; } else { s = d = e - E; }
    int pos = atomicAdd(&cursor[d], 1);
    csr_src[pos] = s;
}

// ---------------- layer 1 GEMM (MFMA f16): h1 = x @ W1^T, fused att halves ----------------
__global__ __launch_bounds__(256) void gemm1_kernel(
    const _Float16* __restrict__ xf, const _Float16* __restrict__ w1f,
    const float* __restrict__ att_src, const float* __restrict__ att_dst,
    _Float16* __restrict__ h1, float* __restrict__ asrc, float* __restrict__ adst, int N) {
    int tid = threadIdx.x;
    int w = tid >> 6, l = tid & 63;
    int g = l >> 4, li = l & 15;
    int n0 = blockIdx.x * 32;
    int row = n0 + (w >> 1) * 16 + li;
    int rowc = row < N ? row : N - 1;
    int colbase = (w & 1) * 128;

    half8 af[4];
    #pragma unroll
    for (int kc = 0; kc < 4; ++kc)
        af[kc] = *(const half8*)&xf[(size_t)rowc * 128 + kc * 32 + g * 8];

    floatx4 acc[8];
    #pragma unroll
    for (int ct = 0; ct < 8; ++ct) acc[ct] = (floatx4){0.f, 0.f, 0.f, 0.f};

    #pragma unroll
    for (int ct = 0; ct < 8; ++ct) {
        int col = colbase + ct * 16 + li;
        const _Float16* wp = &w1f[(size_t)col * 128 + g * 8];
        #pragma unroll
        for (int kc = 0; kc < 4; ++kc) {
            half8 bf = *(const half8*)&wp[kc * 32];
            acc[ct] = __builtin_amdgcn_mfma_f32_16x16x32_f16(af[kc], bf, acc[ct], 0, 0, 0);
        }
    }

    int rowOut0 = n0 + (w >> 1) * 16 + g * 4;
    #pragma unroll
    for (int ct = 0; ct < 8; ++ct) {
        int col = colbase + ct * 16 + li;
        #pragma unroll
        for (int j = 0; j < 4; ++j) {
            int n = rowOut0 + j;
            if (n < N) h1[(size_t)n * 256 + col] = (_Float16)acc[ct][j];
        }
    }
    #pragma unroll
    for (int hh = 0; hh < 4; ++hh) {
        int head = (w & 1) * 4 + hh;
        int c0 = colbase + (2 * hh) * 16 + li;
        float s0 = att_src[c0], s1 = att_src[c0 + 16];
        float d0 = att_dst[c0], d1 = att_dst[c0 + 16];
        #pragma unroll
        for (int j = 0; j < 4; ++j) {
            float ps = acc[2 * hh][j] * s0 + acc[2 * hh + 1][j] * s1;
            float pd = acc[2 * hh][j] * d0 + acc[2 * hh + 1][j] * d1;
            #pragma unroll
            for (int off = 1; off <= 8; off <<= 1) {
                ps += __shfl_xor(ps, off, 64);
                pd += __shfl_xor(pd, off, 64);
            }
            int n = rowOut0 + j;
            if (li == 0 && n < N) {
                asrc[n * 8 + head] = ps;
                adst[n * 8 + head] = pd;
            }
        }
    }
}

// ---------------- layer 1 aggregation: 1 wave/node, no max pass, no LDS ----------------
// lane = slot(1b) x c(5b); c -> channels 8c..8c+7, head = c>>2
__global__ __launch_bounds__(256) void agg1_kernel(
    const _Float16* __restrict__ h1, const float* __restrict__ asrc,
    const float* __restrict__ adst, const int* __restrict__ offsets,
    const int* __restrict__ csr_src, const float* __restrict__ b1,
    _Float16* __restrict__ hout, int N) {
    int tid = threadIdx.x;
    int node = blockIdx.x * 4 + (tid >> 6);
    if (node >= N) return;
    int lane = tid & 63;
    int slot = lane >> 5;
    int c = lane & 31;
    int hd = c >> 2;
    int start = offsets[node];
    int deg = offsets[node + 1] - start;
    float ah = adst[node * 8 + hd];
    float acc[8] = {0, 0, 0, 0, 0, 0, 0, 0};
    float wsum = 0.f;
    const uint4* h14 = (const uint4*)h1;
    int e = slot;
    // 2-deep unroll: edges e, e+2 (per-slot stride is 2)
    while (e + 2 < deg) {
        int sA = csr_src[start + e];
        int sB = csr_src[start + e + 2];
        float vA = asrc[sA * 8 + hd] + ah;
        float vB = asrc[sB * 8 + hd] + ah;
        uint4 uA = h14[(size_t)sA * 32 + c];
        uint4 uB = h14[(size_t)sB * 32 + c];
        vA = vA > 0.f ? vA : NEG_SLOPE * vA;
        vB = vB > 0.f ? vB : NEG_SLOPE * vB;
        float wA = __expf(vA);
        float wB = __expf(vB);
        wsum += wA + wB;
        const _Float16* hA = (const _Float16*)&uA;
        const _Float16* hB = (const _Float16*)&uB;
        #pragma unroll
        for (int j = 0; j < 8; ++j) acc[j] += wA * (float)hA[j] + wB * (float)hB[j];
        e += 4;
    }
    if (e < deg) {
        int s = csr_src[start + e];
        float v = asrc[s * 8 + hd] + ah;
        uint4 u = h14[(size_t)s * 32 + c];
        v = v > 0.f ? v : NEG_SLOPE * v;
        float wgt = __expf(v);
        wsum += wgt;
        const _Float16* hp = (const _Float16*)&u;
        #pragma unroll
        for (int j = 0; j < 8; ++j) acc[j] += wgt * (float)hp[j];
    }
    // slot butterfly
    wsum += __shfl_xor(wsum, 32, 64);
    #pragma unroll
    for (int j = 0; j < 8; ++j) acc[j] += __shfl_xor(acc[j], 32, 64);
    if (slot == 0) {
        float inv = 1.f / (wsum + 1e-16f);
        uint4 o4;
        _Float16* o8 = (_Float16*)&o4;
        #pragma unroll
        for (int j = 0; j < 8; ++j) {
            float o = acc[j] * inv + b1[c * 8 + j];
            o = o > 0.f ? o : (__expf(o) - 1.f);
            o8[j] = (_Float16)o;
        }
        *(uint4*)&hout[(size_t)node * 256 + c * 8] = o4;
    }
}

// ---------------- layer 2 GEMM (MFMA f16): h2 = helu @ W2^T, fused att halves ----------------
__global__ __launch_bounds__(256) void gemm2_kernel(
    const _Float16* __restrict__ hf, const _Float16* __restrict__ w2f,
    const float* __restrict__ att_src, const float* __restrict__ att_dst,
    _Float16* __restrict__ h2, float* __restrict__ asrc, float* __restrict__ adst, int N) {
    __shared__ float a2s[2][2][32];
    int tid = threadIdx.x;
    int w = tid >> 6, l = tid & 63;
    int g = l >> 4, li = l & 15;
    int n0 = blockIdx.x * 32;
    int row = n0 + (w >> 1) * 16 + li;
    int rowc = row < N ? row : N - 1;
    int colbase = (w & 1) * 32;

    floatx4 acc[2];
    acc[0] = (floatx4){0.f, 0.f, 0.f, 0.f};
    acc[1] = (floatx4){0.f, 0.f, 0.f, 0.f};

    #pragma unroll
    for (int kc = 0; kc < 8; ++kc) {
        half8 af = *(const half8*)&hf[(size_t)rowc * 256 + kc * 32 + g * 8];
        #pragma unroll
        for (int ct = 0; ct < 2; ++ct) {
            int col = colbase + ct * 16 + li;
            half8 bf = *(const half8*)&w2f[(size_t)col * 256 + kc * 32 + g * 8];
            acc[ct] = __builtin_amdgcn_mfma_f32_16x16x32_f16(af, bf, acc[ct], 0, 0, 0);
        }
    }

    int rowl0 = (w >> 1) * 16 + g * 4;
    #pragma unroll
    for (int ct = 0; ct < 2; ++ct) {
        int col = colbase + ct * 16 + li;
        #pragma unroll
        for (int j = 0; j < 4; ++j) {
            int n = n0 + rowl0 + j;
            if (n < N) h2[(size_t)n * 64 + col] = (_Float16)acc[ct][j];
        }
    }
    float s0 = att_src[colbase + li], s1 = att_src[colbase + 16 + li];
    float d0 = att_dst[colbase + li], d1 = att_dst[colbase + 16 + li];
    #pragma unroll
    for (int j = 0; j < 4; ++j) {
        float ps = acc[0][j] * s0 + acc[1][j] * s1;
        float pd = acc[0][j] * d0 + acc[1][j] * d1;
        #pragma unroll
        for (int off = 1; off <= 8; off <<= 1) {
            ps += __shfl_xor(ps, off, 64);
            pd += __shfl_xor(pd, off, 64);
        }
        if (li == 0) {
            a2s[w & 1][0][rowl0 + j] = ps;
            a2s[w & 1][1][rowl0 + j] = pd;
        }
    }
    __syncthreads();
    if (tid < 64) {
        int rl = tid & 31, sd = tid >> 5;
        float v = a2s[0][sd][rl] + a2s[1][sd][rl];
        int n = n0 + rl;
        if (n < N) (sd ? adst : asrc)[n] = v;
    }
}

// ---------------- layer 2 aggregation + FC + log_softmax: 1 wave/node, no max pass ----------------
// lane = slot(3b) x c(3b); c -> channels 8c..8c+7
__global__ __launch_bounds__(256) void agg2_kernel(
    const _Float16* __restrict__ h2, const float* __restrict__ asrc,
    const float* __restrict__ adst, const int* __restrict__ offsets,
    const int* __restrict__ csr_src, const float* __restrict__ b2,
    const float* __restrict__ fc_w, const float* __restrict__ fc_b,
    float* __restrict__ out, int N) {
    int tid = threadIdx.x;
    int node = blockIdx.x * 4 + (tid >> 6);
    if (node >= N) return;
    int lane = tid & 63;
    int slot = lane >> 3;
    int c = lane & 7;
    int start = offsets[node];
    int deg = offsets[node + 1] - start;
    float an = adst[node];
    float acc[8] = {0, 0, 0, 0, 0, 0, 0, 0};
    float wsum = 0.f;
    const uint4* h24 = (const uint4*)h2;
    int e = slot;
    while (e + 8 < deg) {
        int sA = csr_src[start + e];
        int sB = csr_src[start + e + 8];
        float vA = asrc[sA] + an;
        float vB = asrc[sB] + an;
        uint4 uA = h24[(size_t)sA * 8 + c];
        uint4 uB = h24[(size_t)sB * 8 + c];
        vA = vA > 0.f ? vA : NEG_SLOPE * vA;
        vB = vB > 0.f ? vB : NEG_SLOPE * vB;
        float wA = __expf(vA);
        float wB = __expf(vB);
        wsum += wA + wB;
        const _Float16* hA = (const _Float16*)&uA;
        const _Float16* hB = (const _Float16*)&uB;
        #pragma unroll
        for (int j = 0; j < 8; ++j) acc[j] += wA * (float)hA[j] + wB * (float)hB[j];
        e += 16;
    }
    if (e < deg) {
        int s = csr_src[start + e];
        float v = asrc[s] + an;
        uint4 u = h24[(size_t)s * 8 + c];
        v = v > 0.f ? v : NEG_SLOPE * v;
        float wgt = __expf(v);
        wsum += wgt;
        const _Float16* hp = (const _Float16*)&u;
        #pragma unroll
        for (int j = 0; j < 8; ++j) acc[j] += wgt * (float)hp[j];
    }
    #pragma unroll
    for (int off = 8; off <= 32; off <<= 1) {
        wsum += __shfl_xor(wsum, off, 64);
        #pragma unroll
        for (int j = 0; j < 8; ++j) acc[j] += __shfl_xor(acc[j], off, 64);
    }
    float inv = 1.f / (wsum + 1e-16f);
    float p0 = 0.f, p1 = 0.f;
    #pragma unroll
    for (int j = 0; j < 8; ++j) {
        float o = acc[j] * inv + b2[c * 8 + j];
        p0 += o * fc_w[c * 8 + j];
        p1 += o * fc_w[64 + c * 8 + j];
    }
    #pragma unroll
    for (int off = 1; off <= 4; off <<= 1) {
        p0 += __shfl_xor(p0, off, 64);
        p1 += __shfl_xor(p1, off, 64);
    }
    if (lane == 0) {
        float l0 = p0 + fc_b[0], l1 = p1 + fc_b[1];
        float mx = fmaxf(l0, l1);
        float lse = mx + logf(expf(l0 - mx) + expf(l1 - mx));
        out[(size_t)node * 2]     = l0 - lse;
        out[(size_t)node * 2 + 1] = l1 - lse;
    }
}

extern "C" void kernel_launch(void* const* d_in, const int* in_sizes, int n_in,
                              void* d_out, int out_size, void* d_ws, size_t ws_size,
                              hipStream_t stream) {
    const float* x        = (const float*)d_in[0];
    const int*   ei       = (const int*)d_in[1];
    const float* W1       = (const float*)d_in[2];
    const float* att_src1 = (const float*)d_in[3];
    const float* att_dst1 = (const float*)d_in[4];
    const float* b1       = (const float*)d_in[5];
    const float* W2       = (const float*)d_in[6];
    const float* att_src2 = (const float*)d_in[7];
    const float* att_dst2 = (const float*)d_in[8];
    const float* b2       = (const float*)d_in[9];
    const float* fc_w     = (const float*)d_in[10];
    const float* fc_b     = (const float*)d_in[11];
    float* out = (float*)d_out;

    int N = in_sizes[0] / 128;
    int E = in_sizes[1] / 2;
    int ET = E + N;
    int nb = (N + 255) / 256;

    char* p = (char*)d_ws;
    auto alloc = [&](size_t bytes) { char* r = p; p += align256(bytes); return r; };
    _Float16* xf16 = (_Float16*)alloc((size_t)N * 128 * 2);
    _Float16* w1f  = (_Float16*)alloc((size_t)256 * 128 * 2);
    _Float16* w2f  = (_Float16*)alloc((size_t)64 * 256 * 2);
    _Float16* h1   = (_Float16*)alloc((size_t)N * 256 * 2);
    _Float16* helu = (_Float16*)alloc((size_t)N * 256 * 2);
    _Float16* h2   = (_Float16*)alloc((size_t)N * 64 * 2);
    float* as1  = (float*)alloc((size_t)N * 8 * 4);
    float* ad1  = (float*)alloc((size_t)N * 8 * 4);
    float* as2  = (float*)alloc((size_t)N * 4);
    float* ad2  = (float*)alloc((size_t)N * 4);
    int* deg    = (int*)alloc((size_t)N * 4);
    int* locinc = (int*)alloc((size_t)N * 4);
    int* bsum   = (int*)alloc((size_t)nb * 4);
    int* total  = (int*)alloc(4);
    int* offs   = (int*)alloc((size_t)(N + 1) * 4);
    int* cursor = (int*)alloc((size_t)N * 4);
    int* csr    = (int*)alloc((size_t)ET * 4);

    hipMemsetAsync(deg, 0, (size_t)N * 4, stream);
    int eb = (ET + 255) / 256;
    cvt_kernel<<<2048, 256, 0, stream>>>(x, xf16, N * 128 / 4);
    cvt_kernel<<<32, 256, 0, stream>>>(W1, w1f, 256 * 128 / 4);
    cvt_kernel<<<16, 256, 0, stream>>>(W2, w2f, 64 * 256 / 4);
    deg_kernel<<<eb, 256, 0, stream>>>(ei, E, N, deg);
    scanA_kernel<<<nb, 256, 0, stream>>>(deg, locinc, bsum, N);
    scanB_kernel<<<1, 256, 0, stream>>>(bsum, nb, total);
    scanC_kernel<<<nb, 256, 0, stream>>>(locinc, deg, bsum, total, offs, cursor, N);
    place_kernel<<<eb, 256, 0, stream>>>(ei, E, N, cursor, csr);
    gemm1_kernel<<<(N + 31) / 32, 256, 0, stream>>>(xf16, w1f, att_src1, att_dst1, h1, as1, ad1, N);
    agg1_kernel<<<(N + 3) / 4, 256, 0, stream>>>(h1, as1, ad1, offs, csr, b1, helu, N);
    gemm2_kernel<<<(N + 31) / 32, 256, 0, stream>>>(helu, w2f, att_src2, att_dst2, h2, as2, ad2, N);
    agg2_kernel<<<(N + 3) / 4, 256, 0, stream>>>(h2, as2, ad2, offs, csr, b2, fc_w, fc_b, out, N);
}

// Round 7
// 346.306 us; speedup vs baseline: 2.2230x; 1.0053x over previous
//
#include <hip/hip_runtime.h>
#include <hip/hip_bf16.h>
#include <math.h>

#define NEG_SLOPE 0.2f

typedef _Float16 half8 __attribute__((ext_vector_type(8)));
typedef float floatx4 __attribute__((ext_vector_type(4)));

static inline size_t align256(size_t x) { return (x + 255) & ~size_t(255); }

// ---------------- prep: cvt W1/W2 to f16 + build combined attention rows ----------------
// w1f: 272 rows x 128 (0..255 = W1, 256..263 = wa_src head h, 264..271 = wa_dst head h)
// w2f: 80 rows x 256 (0..63 = W2, 64 = wa2_src, 65 = wa2_dst, 66..79 = zero)
__global__ __launch_bounds__(256) void prep_kernel(
    const float* __restrict__ W1, const float* __restrict__ W2,
    const float* __restrict__ as1, const float* __restrict__ ad1,
    const float* __restrict__ as2, const float* __restrict__ ad2,
    _Float16* __restrict__ w1f, _Float16* __restrict__ w2f) {
    int t = blockIdx.x * 256 + threadIdx.x;
    if (t < 8192) {  // W1 cvt, 4-wide
        const float4* a4 = (const float4*)W1;
        float4 v = a4[t];
        uint2 o; _Float16* h = (_Float16*)&o;
        h[0] = (_Float16)v.x; h[1] = (_Float16)v.y; h[2] = (_Float16)v.z; h[3] = (_Float16)v.w;
        ((uint2*)w1f)[t] = o;
    } else if (t < 12288) {  // W2 cvt, 4-wide
        int i = t - 8192;
        const float4* a4 = (const float4*)W2;
        float4 v = a4[i];
        uint2 o; _Float16* h = (_Float16*)&o;
        h[0] = (_Float16)v.x; h[1] = (_Float16)v.y; h[2] = (_Float16)v.z; h[3] = (_Float16)v.w;
        ((uint2*)w2f)[i] = o;
    } else if (t < 14336) {  // wa1: 16 rows x 128
        int idx = t - 12288;
        int r = idx >> 7, k = idx & 127;
        int hh = (r < 8) ? r : (r - 8);
        const float* vec = (r < 8) ? as1 : ad1;
        float sum = 0.f;
        for (int c = 0; c < 32; ++c)
            sum += W1[(size_t)(hh * 32 + c) * 128 + k] * vec[hh * 32 + c];
        w1f[(size_t)(256 + r) * 128 + k] = (_Float16)sum;
    } else if (t < 18432) {  // wa2 zone: rows 64..79 x 256
        int idx = t - 14336;
        int rr = idx >> 8, k = idx & 255;
        float val = 0.f;
        if (rr == 0) { for (int c = 0; c < 64; ++c) val += W2[(size_t)c * 256 + k] * as2[c]; }
        else if (rr == 1) { for (int c = 0; c < 64; ++c) val += W2[(size_t)c * 256 + k] * ad2[c]; }
        w2f[(size_t)(64 + rr) * 256 + k] = (_Float16)val;
    }
}

// ---------------- CSR build ----------------
__global__ void deg_kernel(const int* __restrict__ ei, int E, int N, int* __restrict__ deg) {
    int e = blockIdx.x * blockDim.x + threadIdx.x;
    int ET = E + N;
    if (e >= ET) return;
    int d = (e < E) ? ei[E + e] : (e - E);
    atomicAdd(&deg[d], 1);
}

__global__ __launch_bounds__(256) void scanA_kernel(const int* __restrict__ deg,
                                                    int* __restrict__ locinc,
                                                    int* __restrict__ bsum, int n) {
    __shared__ int sd[256];
    int tid = threadIdx.x;
    int i = blockIdx.x * 256 + tid;
    int v = (i < n) ? deg[i] : 0;
    sd[tid] = v;
    __syncthreads();
    for (int off = 1; off < 256; off <<= 1) {
        int t = (tid >= off) ? sd[tid - off] : 0;
        __syncthreads();
        sd[tid] += t;
        __syncthreads();
    }
    if (i < n) locinc[i] = sd[tid];
    if (tid == 255) bsum[blockIdx.x] = sd[255];
}

__global__ __launch_bounds__(256) void scanB_kernel(int* __restrict__ bsum, int nb, int* __restrict__ total) {
    __shared__ int sd[256];
    int tid = threadIdx.x;
    int carry = 0;
    for (int base = 0; base < nb; base += 256) {
        int i = base + tid;
        int v = (i < nb) ? bsum[i] : 0;
        sd[tid] = v;
        __syncthreads();
        for (int off = 1; off < 256; off <<= 1) {
            int t = (tid >= off) ? sd[tid - off] : 0;
            __syncthreads();
            sd[tid] += t;
            __syncthreads();
        }
        if (i < nb) bsum[i] = sd[tid] - v + carry;
        carry += sd[255];
        __syncthreads();
    }
    if (tid == 0) *total = carry;
}

__global__ __launch_bounds__(256) void scanC_kernel(const int* __restrict__ locinc,
                                                    const int* __restrict__ deg,
                                                    const int* __restrict__ bsum,
                                                    const int* __restrict__ total,
                                                    int* __restrict__ offsets,
                                                    int* __restrict__ cursor, int n) {
    int i = blockIdx.x * 256 + threadIdx.x;
    if (i < n) {
        int exc = locinc[i] - deg[i] + bsum[blockIdx.x];
        offsets[i] = exc;
        cursor[i] = exc;
    }
    if (blockIdx.x == 0 && threadIdx.x == 0) offsets[n] = *total;
}

__global__ void place_kernel(const int* __restrict__ ei, int E, int N,
                             int* __restrict__ cursor, int* __restrict__ csr_src) {
    int e = blockIdx.x * blockDim.x + threadIdx.x;
    int ET = E + N;
    if (e >= ET) return;
    int s, d;
    if (e < E) { s = ei[e]; d = ei[E + e]; } else { s = d = e - E; }
    int pos = atomicAdd(&cursor[d], 1);
    csr_src[pos] = s;
}

// ---------------- layer 1 GEMM (MFMA f16): h1 = x @ W1^T, att via appended wa columns ----------------
__global__ __launch_bounds__(256) void gemm1_kernel(
    const float* __restrict__ x, const _Float16* __restrict__ w1f,
    _Float16* __restrict__ h1, float* __restrict__ asrc, float* __restrict__ adst, int N) {
    int tid = threadIdx.x;
    int w = tid >> 6, l = tid & 63;
    int g = l >> 4, li = l & 15;
    int n0 = blockIdx.x * 32;
    int row = n0 + (w >> 1) * 16 + li;
    int rowc = row < N ? row : N - 1;
    int colbase = (w & 1) * 128;

    // A fragments: read x as f32, convert in-register
    const float4* x4 = (const float4*)x;
    half8 af[4];
    #pragma unroll
    for (int kc = 0; kc < 4; ++kc) {
        float4 p0 = x4[(size_t)rowc * 32 + kc * 8 + g * 2];
        float4 p1 = x4[(size_t)rowc * 32 + kc * 8 + g * 2 + 1];
        half8 a;
        a[0] = (_Float16)p0.x; a[1] = (_Float16)p0.y; a[2] = (_Float16)p0.z; a[3] = (_Float16)p0.w;
        a[4] = (_Float16)p1.x; a[5] = (_Float16)p1.y; a[6] = (_Float16)p1.z; a[7] = (_Float16)p1.w;
        af[kc] = a;
    }

    floatx4 acc[8];
    #pragma unroll
    for (int ct = 0; ct < 8; ++ct) acc[ct] = (floatx4){0.f, 0.f, 0.f, 0.f};

    #pragma unroll
    for (int ct = 0; ct < 8; ++ct) {
        int col = colbase + ct * 16 + li;
        const _Float16* wp = &w1f[(size_t)col * 128 + g * 8];
        #pragma unroll
        for (int kc = 0; kc < 4; ++kc) {
            half8 bf = *(const half8*)&wp[kc * 32];
            acc[ct] = __builtin_amdgcn_mfma_f32_16x16x32_f16(af[kc], bf, acc[ct], 0, 0, 0);
        }
    }

    int rowOut0 = n0 + (w >> 1) * 16 + g * 4;
    #pragma unroll
    for (int ct = 0; ct < 8; ++ct) {
        int col = colbase + ct * 16 + li;
        #pragma unroll
        for (int j = 0; j < 4; ++j) {
            int n = rowOut0 + j;
            if (n < N) h1[(size_t)n * 256 + col] = (_Float16)acc[ct][j];
        }
    }
    // attention tile: cols 256..271 (8 src heads, 8 dst heads); waves 0 and 2 only
    if ((w & 1) == 0) {
        floatx4 accA = (floatx4){0.f, 0.f, 0.f, 0.f};
        const _Float16* wp = &w1f[(size_t)(256 + li) * 128 + g * 8];
        #pragma unroll
        for (int kc = 0; kc < 4; ++kc) {
            half8 bf = *(const half8*)&wp[kc * 32];
            accA = __builtin_amdgcn_mfma_f32_16x16x32_f16(af[kc], bf, accA, 0, 0, 0);
        }
        #pragma unroll
        for (int j = 0; j < 4; ++j) {
            int n = rowOut0 + j;
            if (n < N) {
                if (li < 8) asrc[n * 8 + li] = accA[j];
                else        adst[n * 8 + (li - 8)] = accA[j];
            }
        }
    }
}

// ---------------- layer 1 aggregation: 1 wave/node, no max pass, 4-deep unroll ----------------
__global__ __launch_bounds__(256) void agg1_kernel(
    const _Float16* __restrict__ h1, const float* __restrict__ asrc,
    const float* __restrict__ adst, const int* __restrict__ offsets,
    const int* __restrict__ csr_src, const float* __restrict__ b1,
    _Float16* __restrict__ hout, int N) {
    int tid = threadIdx.x;
    int node = blockIdx.x * 4 + (tid >> 6);
    if (node >= N) return;
    int lane = tid & 63;
    int slot = lane >> 5;
    int c = lane & 31;
    int hd = c >> 2;
    int start = offsets[node];
    int deg = offsets[node + 1] - start;
    float ah = adst[node * 8 + hd];
    float acc[8] = {0, 0, 0, 0, 0, 0, 0, 0};
    float wsum = 0.f;
    const uint4* h14 = (const uint4*)h1;
    int e = slot;
    while (e + 6 < deg) {
        int s0 = csr_src[start + e];
        int s1 = csr_src[start + e + 2];
        int s2 = csr_src[start + e + 4];
        int s3 = csr_src[start + e + 6];
        float v0 = asrc[s0 * 8 + hd] + ah;
        float v1 = asrc[s1 * 8 + hd] + ah;
        float v2 = asrc[s2 * 8 + hd] + ah;
        float v3 = asrc[s3 * 8 + hd] + ah;
        uint4 u0 = h14[(size_t)s0 * 32 + c];
        uint4 u1 = h14[(size_t)s1 * 32 + c];
        uint4 u2 = h14[(size_t)s2 * 32 + c];
        uint4 u3 = h14[(size_t)s3 * 32 + c];
        v0 = v0 > 0.f ? v0 : NEG_SLOPE * v0;
        v1 = v1 > 0.f ? v1 : NEG_SLOPE * v1;
        v2 = v2 > 0.f ? v2 : NEG_SLOPE * v2;
        v3 = v3 > 0.f ? v3 : NEG_SLOPE * v3;
        float w0 = __expf(v0), w1 = __expf(v1), w2 = __expf(v2), w3 = __expf(v3);
        wsum += (w0 + w1) + (w2 + w3);
        const _Float16* p0 = (const _Float16*)&u0;
        const _Float16* p1 = (const _Float16*)&u1;
        const _Float16* p2 = (const _Float16*)&u2;
        const _Float16* p3 = (const _Float16*)&u3;
        #pragma unroll
        for (int j = 0; j < 8; ++j)
            acc[j] += (w0 * (float)p0[j] + w1 * (float)p1[j]) + (w2 * (float)p2[j] + w3 * (float)p3[j]);
        e += 8;
    }
    while (e < deg) {
        int s = csr_src[start + e];
        float v = asrc[s * 8 + hd] + ah;
        uint4 u = h14[(size_t)s * 32 + c];
        v = v > 0.f ? v : NEG_SLOPE * v;
        float wgt = __expf(v);
        wsum += wgt;
        const _Float16* hp = (const _Float16*)&u;
        #pragma unroll
        for (int j = 0; j < 8; ++j) acc[j] += wgt * (float)hp[j];
        e += 2;
    }
    wsum += __shfl_xor(wsum, 32, 64);
    #pragma unroll
    for (int j = 0; j < 8; ++j) acc[j] += __shfl_xor(acc[j], 32, 64);
    if (slot == 0) {
        float inv = 1.f / (wsum + 1e-16f);
        uint4 o4;
        _Float16* o8 = (_Float16*)&o4;
        #pragma unroll
        for (int j = 0; j < 8; ++j) {
            float o = acc[j] * inv + b1[c * 8 + j];
            o = o > 0.f ? o : (__expf(o) - 1.f);
            o8[j] = (_Float16)o;
        }
        *(uint4*)&hout[(size_t)node * 256 + c * 8] = o4;
    }
}

// ---------------- layer 2 GEMM (MFMA f16): h2 = helu @ W2^T, att via appended wa2 ----------------
__global__ __launch_bounds__(256) void gemm2_kernel(
    const _Float16* __restrict__ hf, const _Float16* __restrict__ w2f,
    _Float16* __restrict__ h2, float* __restrict__ asrc, float* __restrict__ adst, int N) {
    int tid = threadIdx.x;
    int w = tid >> 6, l = tid & 63;
    int g = l >> 4, li = l & 15;
    int n0 = blockIdx.x * 32;
    int row = n0 + (w >> 1) * 16 + li;
    int rowc = row < N ? row : N - 1;
    int colbase = (w & 1) * 32;
    bool doAtt = (w & 1) == 0;

    floatx4 acc0 = (floatx4){0.f, 0.f, 0.f, 0.f};
    floatx4 acc1 = (floatx4){0.f, 0.f, 0.f, 0.f};
    floatx4 accA = (floatx4){0.f, 0.f, 0.f, 0.f};

    #pragma unroll
    for (int kc = 0; kc < 8; ++kc) {
        half8 af = *(const half8*)&hf[(size_t)rowc * 256 + kc * 32 + g * 8];
        half8 b0 = *(const half8*)&w2f[(size_t)(colbase + li) * 256 + kc * 32 + g * 8];
        half8 b1 = *(const half8*)&w2f[(size_t)(colbase + 16 + li) * 256 + kc * 32 + g * 8];
        acc0 = __builtin_amdgcn_mfma_f32_16x16x32_f16(af, b0, acc0, 0, 0, 0);
        acc1 = __builtin_amdgcn_mfma_f32_16x16x32_f16(af, b1, acc1, 0, 0, 0);
        if (doAtt) {
            half8 bA = *(const half8*)&w2f[(size_t)(64 + li) * 256 + kc * 32 + g * 8];
            accA = __builtin_amdgcn_mfma_f32_16x16x32_f16(af, bA, accA, 0, 0, 0);
        }
    }

    int rowOut0 = n0 + (w >> 1) * 16 + g * 4;
    #pragma unroll
    for (int j = 0; j < 4; ++j) {
        int n = rowOut0 + j;
        if (n < N) {
            h2[(size_t)n * 64 + colbase + li]      = (_Float16)acc0[j];
            h2[(size_t)n * 64 + colbase + 16 + li] = (_Float16)acc1[j];
        }
    }
    if (doAtt && li < 2) {
        #pragma unroll
        for (int j = 0; j < 4; ++j) {
            int n = rowOut0 + j;
            if (n < N) (li == 0 ? asrc : adst)[n] = accA[j];
        }
    }
}

// ---------------- layer 2 aggregation + FC + log_softmax: 1 wave/node, 4-deep unroll ----------------
__global__ __launch_bounds__(256) void agg2_kernel(
    const _Float16* __restrict__ h2, const float* __restrict__ asrc,
    const float* __restrict__ adst, const int* __restrict__ offsets,
    const int* __restrict__ csr_src, const float* __restrict__ b2,
    const float* __restrict__ fc_w, const float* __restrict__ fc_b,
    float* __restrict__ out, int N) {
    int tid = threadIdx.x;
    int node = blockIdx.x * 4 + (tid >> 6);
    if (node >= N) return;
    int lane = tid & 63;
    int slot = lane >> 3;
    int c = lane & 7;
    int start = offsets[node];
    int deg = offsets[node + 1] - start;
    float an = adst[node];
    float acc[8] = {0, 0, 0, 0, 0, 0, 0, 0};
    float wsum = 0.f;
    const uint4* h24 = (const uint4*)h2;
    int e = slot;
    while (e + 24 < deg) {
        int s0 = csr_src[start + e];
        int s1 = csr_src[start + e + 8];
        int s2 = csr_src[start + e + 16];
        int s3 = csr_src[start + e + 24];
        float v0 = asrc[s0] + an, v1 = asrc[s1] + an, v2 = asrc[s2] + an, v3 = asrc[s3] + an;
        uint4 u0 = h24[(size_t)s0 * 8 + c];
        uint4 u1 = h24[(size_t)s1 * 8 + c];
        uint4 u2 = h24[(size_t)s2 * 8 + c];
        uint4 u3 = h24[(size_t)s3 * 8 + c];
        v0 = v0 > 0.f ? v0 : NEG_SLOPE * v0;
        v1 = v1 > 0.f ? v1 : NEG_SLOPE * v1;
        v2 = v2 > 0.f ? v2 : NEG_SLOPE * v2;
        v3 = v3 > 0.f ? v3 : NEG_SLOPE * v3;
        float w0 = __expf(v0), w1 = __expf(v1), w2 = __expf(v2), w3 = __expf(v3);
        wsum += (w0 + w1) + (w2 + w3);
        const _Float16* p0 = (const _Float16*)&u0;
        const _Float16* p1 = (const _Float16*)&u1;
        const _Float16* p2 = (const _Float16*)&u2;
        const _Float16* p3 = (const _Float16*)&u3;
        #pragma unroll
        for (int j = 0; j < 8; ++j)
            acc[j] += (w0 * (float)p0[j] + w1 * (float)p1[j]) + (w2 * (float)p2[j] + w3 * (float)p3[j]);
        e += 32;
    }
    while (e < deg) {
        int s = csr_src[start + e];
        float v = asrc[s] + an;
        uint4 u = h24[(size_t)s * 8 + c];
        v = v > 0.f ? v : NEG_SLOPE * v;
        float wgt = __expf(v);
        wsum += wgt;
        const _Float16* hp = (const _Float16*)&u;
        #pragma unroll
        for (int j = 0; j < 8; ++j) acc[j] += wgt * (float)hp[j];
        e += 8;
    }
    #pragma unroll
    for (int off = 8; off <= 32; off <<= 1) {
        wsum += __shfl_xor(wsum, off, 64);
        #pragma unroll
        for (int j = 0; j < 8; ++j) acc[j] += __shfl_xor(acc[j], off, 64);
    }
    float inv = 1.f / (wsum + 1e-16f);
    float p0 = 0.f, p1 = 0.f;
    #pragma unroll
    for (int j = 0; j < 8; ++j) {
        float o = acc[j] * inv + b2[c * 8 + j];
        p0 += o * fc_w[c * 8 + j];
        p1 += o * fc_w[64 + c * 8 + j];
    }
    #pragma unroll
    for (int off = 1; off <= 4; off <<= 1) {
        p0 += __shfl_xor(p0, off, 64);
        p1 += __shfl_xor(p1, off, 64);
    }
    if (lane == 0) {
        float l0 = p0 + fc_b[0], l1 = p1 + fc_b[1];
        float mx = fmaxf(l0, l1);
        float lse = mx + logf(expf(l0 - mx) + expf(l1 - mx));
        out[(size_t)node * 2]     = l0 - lse;
        out[(size_t)node * 2 + 1] = l1 - lse;
    }
}

extern "C" void kernel_launch(void* const* d_in, const int* in_sizes, int n_in,
                              void* d_out, int out_size, void* d_ws, size_t ws_size,
                              hipStream_t stream) {
    const float* x        = (const float*)d_in[0];
    const int*   ei       = (const int*)d_in[1];
    const float* W1       = (const float*)d_in[2];
    const float* att_src1 = (const float*)d_in[3];
    const float* att_dst1 = (const float*)d_in[4];
    const float* b1       = (const float*)d_in[5];
    const float* W2       = (const float*)d_in[6];
    const float* att_src2 = (const float*)d_in[7];
    const float* att_dst2 = (const float*)d_in[8];
    const float* b2       = (const float*)d_in[9];
    const float* fc_w     = (const float*)d_in[10];
    const float* fc_b     = (const float*)d_in[11];
    float* out = (float*)d_out;

    int N = in_sizes[0] / 128;
    int E = in_sizes[1] / 2;
    int ET = E + N;
    int nb = (N + 255) / 256;

    char* p = (char*)d_ws;
    auto alloc = [&](size_t bytes) { char* r = p; p += align256(bytes); return r; };
    _Float16* w1f  = (_Float16*)alloc((size_t)272 * 128 * 2);
    _Float16* w2f  = (_Float16*)alloc((size_t)80 * 256 * 2);
    _Float16* h1   = (_Float16*)alloc((size_t)N * 256 * 2);
    _Float16* helu = (_Float16*)alloc((size_t)N * 256 * 2);
    _Float16* h2   = (_Float16*)alloc((size_t)N * 64 * 2);
    float* as1  = (float*)alloc((size_t)N * 8 * 4);
    float* ad1  = (float*)alloc((size_t)N * 8 * 4);
    float* as2  = (float*)alloc((size_t)N * 4);
    float* ad2  = (float*)alloc((size_t)N * 4);
    int* deg    = (int*)alloc((size_t)N * 4);
    int* locinc = (int*)alloc((size_t)N * 4);
    int* bsum   = (int*)alloc((size_t)nb * 4);
    int* total  = (int*)alloc(4);
    int* offs   = (int*)alloc((size_t)(N + 1) * 4);
    int* cursor = (int*)alloc((size_t)N * 4);
    int* csr    = (int*)alloc((size_t)ET * 4);

    hipMemsetAsync(deg, 0, (size_t)N * 4, stream);
    int eb = (ET + 255) / 256;
    prep_kernel<<<72, 256, 0, stream>>>(W1, W2, att_src1, att_dst1, att_src2, att_dst2, w1f, w2f);
    deg_kernel<<<eb, 256, 0, stream>>>(ei, E, N, deg);
    scanA_kernel<<<nb, 256, 0, stream>>>(deg, locinc, bsum, N);
    scanB_kernel<<<1, 256, 0, stream>>>(bsum, nb, total);
    scanC_kernel<<<nb, 256, 0, stream>>>(locinc, deg, bsum, total, offs, cursor, N);
    place_kernel<<<eb, 256, 0, stream>>>(ei, E, N, cursor, csr);
    gemm1_kernel<<<(N + 31) / 32, 256, 0, stream>>>(x, w1f, h1, as1, ad1, N);
    agg1_kernel<<<(N + 3) / 4, 256, 0, stream>>>(h1, as1, ad1, offs, csr, b1, helu, N);
    gemm2_kernel<<<(N + 31) / 32, 256, 0, stream>>>(helu, w2f, h2, as2, ad2, N);
    agg2_kernel<<<(N + 3) / 4, 256, 0, stream>>>(h2, as2, ad2, offs, csr, b2, fc_w, fc_b, out, N);
}